// Round 16
// baseline (468.965 us; speedup 1.0000x reference)
//
#include <hip/hip_runtime.h>
#include <hip/hip_bf16.h>
#include <math.h>

constexpr int S_ = 2048, H_ = 1024, NH_ = 16, KVH_ = 8, HD_ = 64;
constexpr int E_ = 8, I_ = 3584;
constexpr int KSLC = 4;
constexpr float EPS_ = 1e-6f;
constexpr float THETA_ = 1000000.0f;

#define SDIV(a,b) (((a)+(b)-1)/(b))

typedef __attribute__((ext_vector_type(8))) short bf16x8;
typedef __attribute__((ext_vector_type(4))) float f32x4;
typedef __attribute__((ext_vector_type(4))) int i32x4;

__device__ inline unsigned pkbf(float a, float b) {
    unsigned r;
    asm("v_cvt_pk_bf16_f32 %0, %1, %2" : "=v"(r) : "v"(a), "v"(b));
    return r;
}
__device__ inline unsigned short f2bf(float f) {
    unsigned u = __float_as_uint(f);
    u += 0x7FFF + ((u >> 16) & 1);
    return (unsigned short)(u >> 16);
}
__device__ inline float bf2f(unsigned short v) {
    return __uint_as_float((unsigned)v << 16);
}

__device__ inline void gload16u(const void* gsrc, char* ldsArr, int uoff) {
    int off = __builtin_amdgcn_readfirstlane(uoff);
    __builtin_amdgcn_global_load_lds(
        (__attribute__((address_space(1))) void*)(gsrc),
        (__attribute__((address_space(3))) void*)(ldsArr + off), 16, 0, 0);
}
__device__ inline void vmdrain() {
    asm volatile("s_waitcnt vmcnt(0)" ::: "memory");
}

template<bool WB>
__device__ inline int4 loadW16(const void* W, size_t elemOff) {
    if constexpr (WB) {
        return *(const int4*)((const unsigned short*)W + elemOff);
    } else {
        const float* s = (const float*)W + elemOff;
        float4 f0 = *(const float4*)s, f1 = *(const float4*)(s + 4);
        return make_int4(pkbf(f0.x, f0.y), pkbf(f0.z, f0.w),
                         pkbf(f1.x, f1.y), pkbf(f1.z, f1.w));
    }
}

// ---------------- merged conv for the 3 big MoE weights: NT loads/stores, 16 elem/iter
__global__ __launch_bounds__(256) void conv3(const float* __restrict__ a,
                                             const float* __restrict__ b,
                                             const float* __restrict__ c,
                                             unsigned short* __restrict__ oa,
                                             unsigned short* __restrict__ ob,
                                             unsigned short* __restrict__ oc,
                                             long n16)
{
    long total = 3 * n16;
    long stride = (long)gridDim.x * 256;
    for (long u = (long)blockIdx.x * 256 + threadIdx.x; u < total; u += stride) {
        int t = (int)(u / n16);
        long v = u - (long)t * n16;
        const float* in = ((t == 0) ? a : (t == 1) ? b : c) + v * 16;
        unsigned short* out = ((t == 0) ? oa : (t == 1) ? ob : oc) + v * 16;
        f32x4 f0 = __builtin_nontemporal_load((const f32x4*)in);
        f32x4 f1 = __builtin_nontemporal_load((const f32x4*)(in + 4));
        f32x4 f2 = __builtin_nontemporal_load((const f32x4*)(in + 8));
        f32x4 f3 = __builtin_nontemporal_load((const f32x4*)(in + 12));
        i32x4 o0, o1;
        o0.x = (int)pkbf(f0.x, f0.y); o0.y = (int)pkbf(f0.z, f0.w);
        o0.z = (int)pkbf(f1.x, f1.y); o0.w = (int)pkbf(f1.z, f1.w);
        o1.x = (int)pkbf(f2.x, f2.y); o1.y = (int)pkbf(f2.z, f2.w);
        o1.z = (int)pkbf(f3.x, f3.y); o1.w = (int)pkbf(f3.z, f3.w);
        __builtin_nontemporal_store(o0, (i32x4*)out);
        __builtin_nontemporal_store(o1, (i32x4*)(out + 8));
    }
}

// ---------------- merged conv for wq|wk|wv -> wqkvb and wo -> wob
__global__ __launch_bounds__(256) void conv_qkvo(const float* __restrict__ wq,
                                                 const float* __restrict__ wk,
                                                 const float* __restrict__ wv,
                                                 const float* __restrict__ wo,
                                                 unsigned short* __restrict__ wqkvb,
                                                 unsigned short* __restrict__ wob)
{
    const long NQ = (long)NH_ * HD_ * H_ / 8;      // 131072
    const long NK = (long)KVH_ * HD_ * H_ / 8;     // 65536
    long u = (long)blockIdx.x * 256 + threadIdx.x; // grid sized exactly
    const float* in; unsigned short* out;
    if (u < NQ)                { in = wq + u * 8;               out = wqkvb + u * 8; }
    else if (u < NQ + NK)      { long v = u - NQ;      in = wk + v * 8; out = wqkvb + (NQ + v) * 8; }
    else if (u < NQ + 2 * NK)  { long v = u - NQ - NK; in = wv + v * 8; out = wqkvb + (NQ + NK + v) * 8; }
    else                       { long v = u - NQ - 2 * NK; in = wo + v * 8; out = wob + v * 8; }
    float4 f0 = *(const float4*)in, f1 = *(const float4*)(in + 4);
    *(int4*)out = make_int4(pkbf(f0.x, f0.y), pkbf(f0.z, f0.w),
                            pkbf(f1.x, f1.y), pkbf(f1.z, f1.w));
}

// ---------------- RMSNorm (fp32 out and bf16 out both optional)
__global__ __launch_bounds__(256) void rmsnorm_k(const float* __restrict__ x,
                                                 const float* __restrict__ w,
                                                 float* __restrict__ out,
                                                 unsigned short* __restrict__ outb)
{
    int row = blockIdx.x;
    int tid = threadIdx.x;
    const float* xr = x + (size_t)row * H_;
    float4 v = *(const float4*)&xr[tid * 4];
    float ss = v.x*v.x + v.y*v.y + v.z*v.z + v.w*v.w;
#pragma unroll
    for (int off = 32; off > 0; off >>= 1) ss += __shfl_xor(ss, off);
    __shared__ float red[4];
    if ((tid & 63) == 0) red[tid >> 6] = ss;
    __syncthreads();
    float tot = red[0] + red[1] + red[2] + red[3];
    float r = rsqrtf(tot / (float)H_ + EPS_);
    float4 wv = *(const float4*)&w[tid * 4];
    float4 o;
    o.x = v.x * r * wv.x; o.y = v.y * r * wv.y;
    o.z = v.z * r * wv.z; o.w = v.w * r * wv.w;
    if (out) *(float4*)&out[(size_t)row * H_ + tid * 4] = o;
    if (outb) {
        uint2 pk = make_uint2(pkbf(o.x, o.y), pkbf(o.z, o.w));
        *(uint2*)&outb[(size_t)row * H_ + tid * 4] = pk;
    }
}

// ---------------- Fused RMSNorm2 + router (WB path)
__global__ __launch_bounds__(256) void rms2router(const float* __restrict__ x,
                                                  const float* __restrict__ w,
                                                  const float* __restrict__ gw,
                                                  unsigned short* __restrict__ outb,
                                                  int* __restrict__ cnt,
                                                  int* __restrict__ elist,
                                                  int* __restrict__ eslot,
                                                  float* __restrict__ wslot)
{
    int row = blockIdx.x;
    int tid = threadIdx.x;
    const float* xr = x + (size_t)row * H_;
    float4 v = *(const float4*)&xr[tid * 4];
    float ss = v.x*v.x + v.y*v.y + v.z*v.z + v.w*v.w;
#pragma unroll
    for (int off = 32; off > 0; off >>= 1) ss += __shfl_xor(ss, off);
    __shared__ float red[4];
    __shared__ float redE[4][8];
    if ((tid & 63) == 0) red[tid >> 6] = ss;
    __syncthreads();
    float tot = red[0] + red[1] + red[2] + red[3];
    float r = rsqrtf(tot / (float)H_ + EPS_);
    float4 wv = *(const float4*)&w[tid * 4];
    float o0 = v.x * r * wv.x, o1 = v.y * r * wv.y;
    float o2 = v.z * r * wv.z, o3 = v.w * r * wv.w;
    uint2 pk = make_uint2(pkbf(o0, o1), pkbf(o2, o3));
    *(uint2*)&outb[(size_t)row * H_ + tid * 4] = pk;

    int col = tid * 4;
    float part[E_];
#pragma unroll
    for (int e = 0; e < E_; ++e) {
        const float* g = gw + (size_t)e * H_ + col;
        part[e] = o0 * g[0] + o1 * g[1] + o2 * g[2] + o3 * g[3];
    }
#pragma unroll
    for (int e = 0; e < E_; ++e)
#pragma unroll
        for (int off = 32; off > 0; off >>= 1) part[e] += __shfl_xor(part[e], off);
    if ((tid & 63) == 0)
#pragma unroll
        for (int e = 0; e < E_; ++e) redE[tid >> 6][e] = part[e];
    __syncthreads();
    if (tid == 0) {
        float lg[E_];
#pragma unroll
        for (int e = 0; e < E_; ++e)
            lg[e] = redE[0][e] + redE[1][e] + redE[2][e] + redE[3][e];
        float mx = lg[0];
#pragma unroll
        for (int e = 1; e < E_; ++e) mx = fmaxf(mx, lg[e]);
        float rw[E_]; float ssum = 0.f;
#pragma unroll
        for (int e = 0; e < E_; ++e) { rw[e] = expf(lg[e] - mx); ssum += rw[e]; }
#pragma unroll
        for (int e = 0; e < E_; ++e) rw[e] /= ssum;
        float best = -1.f; int ba = 0, bb = 1;
        for (int a = 0; a < E_; ++a)
            for (int b = a + 1; b < E_; ++b) {
                float scv = rw[a] + rw[b];
                if (scv > best) { best = scv; ba = a; bb = b; }
            }
        float wa = rw[ba], wb = rw[bb], wsum = wa + wb;
        wa /= wsum; wb /= wsum;
        int n = row;
        int p = atomicAdd(&cnt[ba], 1);
        elist[ba * S_ + p] = n; eslot[ba * S_ + p] = 2 * n;
        p = atomicAdd(&cnt[bb], 1);
        elist[bb * S_ + p] = n; eslot[bb * S_ + p] = 2 * n + 1;
        wslot[2 * n] = wa; wslot[2 * n + 1] = wb;
    }
}

// ---------------- Dense g-style GEMM (WB path): 128(M) x 64(N), BK=64. Hoisted addrs.
template<bool OUTF32>
__global__ __launch_bounds__(256) void dense_g(const unsigned short* __restrict__ A,
                                               const unsigned short* __restrict__ B,
                                               const float* __restrict__ Res,
                                               void* __restrict__ C,
                                               int K, int ldC)
{
    int m0 = blockIdx.y * 128, n0 = blockIdx.x * 64;
    int tid = threadIdx.x;
    __shared__ char As[16384], Bs[8192];
    int lane = tid & 63, w = tid >> 6, wm = w >> 1, wn = w & 1;
    int lm = lane & 15, lk = lane >> 4;
    int wb16 = (tid & ~63) * 16;

    const unsigned short* aSrc[4];
    const unsigned short* bSrc[2];
#pragma unroll
    for (int it = 0; it < 4; ++it) {
        int g = tid + it * 256, row = g >> 3, kg = g & 7;
        int kgs = kg ^ (row & 7);
        aSrc[it] = A + (size_t)(m0 + row) * K + kgs * 8;
    }
#pragma unroll
    for (int it = 0; it < 2; ++it) {
        int g = tid + it * 256, row = g >> 3, kg = g & 7;
        int kgs = kg ^ (row & 7);
        bSrc[it] = B + (size_t)(n0 + row) * K + kgs * 8;
    }

    f32x4 z = {0.f, 0.f, 0.f, 0.f};
    f32x4 acc[4][2];
#pragma unroll
    for (int mf = 0; mf < 4; ++mf)
#pragma unroll
        for (int nf = 0; nf < 2; ++nf) acc[mf][nf] = z;

    for (int kt = 0; kt < K / 64; ++kt) {
        int kb = kt * 64;
#pragma unroll
        for (int it = 0; it < 4; ++it)
            gload16u(aSrc[it] + kb, As, wb16 + it * 4096);
#pragma unroll
        for (int it = 0; it < 2; ++it)
            gload16u(bSrc[it] + kb, Bs, wb16 + it * 4096);
        vmdrain();
        __syncthreads();
#pragma unroll
        for (int ks = 0; ks < 2; ++ks) {
            bf16x8 af[4];
#pragma unroll
            for (int mf = 0; mf < 4; ++mf) {
                int row = wm * 64 + mf * 16 + lm;
                af[mf] = *(const bf16x8*)(As + row * 128 + ((ks * 64 + lk * 16) ^ ((row & 7) << 4)));
            }
#pragma unroll
            for (int nf = 0; nf < 2; ++nf) {
                int brow = wn * 32 + nf * 16 + lm;
                bf16x8 bf = *(const bf16x8*)(Bs + brow * 128 + ((ks * 64 + lk * 16) ^ ((brow & 7) << 4)));
#pragma unroll
                for (int mf = 0; mf < 4; ++mf)
                    acc[mf][nf] = __builtin_amdgcn_mfma_f32_16x16x32_bf16(af[mf], bf, acc[mf][nf], 0, 0, 0);
            }
        }
        __syncthreads();
    }

#pragma unroll
    for (int mf = 0; mf < 4; ++mf)
#pragma unroll
        for (int nf = 0; nf < 2; ++nf) {
            int col = n0 + wn * 32 + nf * 16 + lm;
#pragma unroll
            for (int j = 0; j < 4; ++j) {
                int row = m0 + wm * 64 + mf * 16 + lk * 4 + j;
                float v = acc[mf][nf][j];
                if constexpr (OUTF32) {
                    float r = Res ? Res[(size_t)row * ldC + col] : 0.0f;
                    ((float*)C)[(size_t)row * ldC + col] = v + r;
                } else {
                    ((unsigned short*)C)[(size_t)row * ldC + col] = f2bf(v);
                }
            }
        }
}

// ---------------- Dense bf16-MFMA GEMM (reg-staged; WB=false fallback)
template<bool WB>
__global__ __launch_bounds__(256) void dense_mfma(const float* __restrict__ A,
                                                  const void* __restrict__ Bw,
                                                  const float* __restrict__ Res,
                                                  float* __restrict__ C,
                                                  int M, int N, int K)
{
    __shared__ char As[16384], Bs[16384];
    int tid = threadIdx.x;
    int m0 = blockIdx.y * 128, n0 = blockIdx.x * 128;
    int lane = tid & 63, w = tid >> 6, wm = w >> 1, wn = w & 1;
    int lm = lane & 15, lk = lane >> 4;

    int4 rA[4], rB[4];
    auto loadAll = [&](int kb) {
#pragma unroll
        for (int it = 0; it < 4; ++it) {
            int g = tid + it * 256, row = g >> 3, kg = g & 7;
            const float* s = A + (size_t)(m0 + row) * K + kb + kg * 8;
            float4 f0 = *(const float4*)s, f1 = *(const float4*)(s + 4);
            rA[it] = make_int4(pkbf(f0.x, f0.y), pkbf(f0.z, f0.w),
                               pkbf(f1.x, f1.y), pkbf(f1.z, f1.w));
            rB[it] = loadW16<WB>(Bw, (size_t)(n0 + row) * K + kb + kg * 8);
        }
    };
    auto writeAll = [&]() {
#pragma unroll
        for (int it = 0; it < 4; ++it) {
            int g = tid + it * 256, row = g >> 3, kg = g & 7;
            int byte = row * 128 + ((kg * 16) ^ ((row & 7) << 4));
            *(int4*)(As + byte) = rA[it];
            *(int4*)(Bs + byte) = rB[it];
        }
    };

    f32x4 z = {0.f, 0.f, 0.f, 0.f};
    f32x4 acc[4][4];
#pragma unroll
    for (int mf = 0; mf < 4; ++mf)
#pragma unroll
        for (int nf = 0; nf < 4; ++nf) acc[mf][nf] = z;

    loadAll(0);
    for (int kt = 0; kt < K / 64; ++kt) {
        __syncthreads();
        writeAll();
        __syncthreads();
        if (kt + 1 < K / 64) loadAll((kt + 1) * 64);
#pragma unroll
        for (int ks = 0; ks < 2; ++ks) {
            bf16x8 af[4];
#pragma unroll
            for (int mf = 0; mf < 4; ++mf) {
                int row = wm * 64 + mf * 16 + lm;
                af[mf] = *(const bf16x8*)(As + row * 128 + ((ks * 64 + lk * 16) ^ ((row & 7) << 4)));
            }
#pragma unroll
            for (int nf = 0; nf < 4; ++nf) {
                int brow = wn * 64 + nf * 16 + lm;
                bf16x8 bf = *(const bf16x8*)(Bs + brow * 128 + ((ks * 64 + lk * 16) ^ ((brow & 7) << 4)));
#pragma unroll
                for (int mf = 0; mf < 4; ++mf)
                    acc[mf][nf] = __builtin_amdgcn_mfma_f32_16x16x32_bf16(af[mf], bf, acc[mf][nf], 0, 0, 0);
            }
        }
    }

#pragma unroll
    for (int mf = 0; mf < 4; ++mf)
#pragma unroll
        for (int nf = 0; nf < 4; ++nf) {
            int col = n0 + wn * 64 + nf * 16 + lm;
#pragma unroll
            for (int j = 0; j < 4; ++j) {
                int row = m0 + wm * 64 + mf * 16 + lk * 4 + j;
                float r = Res ? Res[(size_t)row * N + col] : 0.0f;
                C[(size_t)row * N + col] = acc[mf][nf][j] + r;
            }
        }
}

// ---------------- RoPE + bf16 (WB path): reads fused bf16 qkvb [S][2048]
__global__ __launch_bounds__(256) void rope_conv_b(const unsigned short* __restrict__ qkvb,
                                                   unsigned short* __restrict__ qbf,
                                                   unsigned short* __restrict__ kbf)
{
    int idx = blockIdx.x * 256 + threadIdx.x;
    const int totq = S_ * NH_ * 32;
    const int tot = totq + S_ * KVH_ * 32;
    if (idx >= tot) return;
    const unsigned short* src; unsigned short* dst; int s, di; float sc;
    if (idx < totq) {
        s = idx / (NH_ * 32); int r = idx % (NH_ * 32); int h = r >> 5;
        src = qkvb + (size_t)s * 2048 + h * 64;
        dst = qbf + ((size_t)s * NH_ + h) * HD_;
        di = r & 31; sc = 0.125f;
    } else {
        int j2 = idx - totq;
        s = j2 / (KVH_ * 32); int r = j2 % (KVH_ * 32); int kvh = r >> 5;
        src = qkvb + (size_t)s * 2048 + 1024 + kvh * 64;
        dst = kbf + ((size_t)s * KVH_ + kvh) * HD_;
        di = r & 31; sc = 1.0f;
    }
    float invf = powf(THETA_, -(2.0f * di) / (float)HD_);
    float ang = (float)s * invf;
    float c = cosf(ang), sn = sinf(ang);
    float x0 = bf2f(src[di]), x1 = bf2f(src[di + 32]);
    dst[di]      = f2bf((x0 * c - x1 * sn) * sc);
    dst[di + 32] = f2bf((x1 * c + x0 * sn) * sc);
}

// ---------------- V transpose (WB path): V from qkvb cols [1536..2048)
__global__ __launch_bounds__(256) void v_trans_b(const unsigned short* __restrict__ qkvb,
                                                 unsigned short* __restrict__ vtb)
{
    int t0 = blockIdx.x * 64, kvh = blockIdx.y;
    __shared__ unsigned short T[64][64];
    int tid = threadIdx.x;
    int k = tid >> 2, d0 = (tid & 3) * 16;
    const unsigned short* src = qkvb + (size_t)(t0 + k) * 2048 + 1536 + kvh * 64 + d0;
    *(int4*)&T[k][d0]     = *(const int4*)(src);
    *(int4*)&T[k][d0 + 8] = *(const int4*)(src + 8);
    __syncthreads();
    int d = tid >> 2, s0 = (tid & 3) * 16;
    unsigned short tmp[16] __attribute__((aligned(16)));
#pragma unroll
    for (int x = 0; x < 16; ++x) {
        int s = s0 + x;
        int key = 16 * (s & 3) + (s >> 2);
        tmp[x] = T[key][d];
    }
    unsigned short* dst = vtb + ((size_t)kvh * HD_ + d) * S_ + t0 + s0;
    *(int4*)(dst)     = *(int4*)(tmp);
    *(int4*)(dst + 8) = *(int4*)(tmp + 8);
}

// ---------------- RoPE + bf16 convert (fallback: fp32 q/k inputs)
__global__ __launch_bounds__(256) void rope_conv(const float* __restrict__ q,
                                                 const float* __restrict__ k,
                                                 unsigned short* __restrict__ qbf,
                                                 unsigned short* __restrict__ kbf)
{
    int idx = blockIdx.x * 256 + threadIdx.x;
    const int totq = S_ * NH_ * 32;
    const int tot = totq + S_ * KVH_ * 32;
    if (idx >= tot) return;
    const float* base; unsigned short* obase; int s, di; float sc;
    if (idx < totq) {
        s = idx / (NH_ * 32); int r = idx % (NH_ * 32);
        size_t o = ((size_t)s * NH_ + (r >> 5)) * HD_;
        base = q + o; obase = qbf + o; di = r & 31; sc = 0.125f;
    } else {
        int j2 = idx - totq;
        s = j2 / (KVH_ * 32); int r = j2 % (KVH_ * 32);
        size_t o = ((size_t)s * KVH_ + (r >> 5)) * HD_;
        base = k + o; obase = kbf + o; di = r & 31; sc = 1.0f;
    }
    float invf = powf(THETA_, -(2.0f * di) / (float)HD_);
    float ang = (float)s * invf;
    float c = cosf(ang), sn = sinf(ang);
    float x0 = base[di], x1 = base[di + 32];
    obase[di]      = f2bf((x0 * c - x1 * sn) * sc);
    obase[di + 32] = f2bf((x1 * c + x0 * sn) * sc);
}

// ---------------- V transpose (fallback: fp32 V input)
__global__ __launch_bounds__(256) void v_trans(const float* __restrict__ v,
                                               unsigned short* __restrict__ vtb)
{
    int t0 = blockIdx.x * 64, kvh = blockIdx.y;
    __shared__ unsigned short T[64][64];
    int tid = threadIdx.x;
    int k = tid >> 2, d0 = (tid & 3) * 16;
    const float* src = v + ((size_t)(t0 + k) * KVH_ + kvh) * HD_ + d0;
#pragma unroll
    for (int x = 0; x < 4; ++x) {
        float4 f = *(const float4*)(src + x * 4);
        T[k][d0 + x*4 + 0] = f2bf(f.x);
        T[k][d0 + x*4 + 1] = f2bf(f.y);
        T[k][d0 + x*4 + 2] = f2bf(f.z);
        T[k][d0 + x*4 + 3] = f2bf(f.w);
    }
    __syncthreads();
    int d = tid >> 2, s0 = (tid & 3) * 16;
    unsigned short tmp[16] __attribute__((aligned(16)));
#pragma unroll
    for (int x = 0; x < 16; ++x) {
        int s = s0 + x;
        int key = 16 * (s & 3) + (s >> 2);
        tmp[x] = T[key][d];
    }
    unsigned short* dst = vtb + ((size_t)kvh * HD_ + d) * S_ + t0 + s0;
    *(int4*)(dst)     = *(int4*)(tmp);
    *(int4*)(dst + 8) = *(int4*)(tmp + 8);
}

// ---------------- MFMA flash attention (fp32 ctx optional; defer-max softmax)
__global__ __launch_bounds__(256) void attn_mfma(const unsigned short* __restrict__ qbf,
                                                 const unsigned short* __restrict__ kbf,
                                                 const unsigned short* __restrict__ vtb,
                                                 float* __restrict__ ctx,
                                                 unsigned short* __restrict__ ctxb)
{
    __shared__ char Ps[4 * 2048];
    int pair = blockIdx.x, h = blockIdx.y, z = blockIdx.z;
    int qb = z ? (31 - pair) : pair;
    int q0 = qb * 64;
    int kvh = h >> 1;
    int tid = threadIdx.x;
    int w = tid >> 6, lane = tid & 63;
    int lm = lane & 15, lk = lane >> 4;
    char* myP = Ps + w * 2048;

    bf16x8 qf[2];
    const unsigned short* qrow = qbf + ((size_t)(q0 + w * 16 + lm) * NH_ + h) * HD_;
#pragma unroll
    for (int ks = 0; ks < 2; ++ks)
        qf[ks] = *(const bf16x8*)(qrow + ks * 32 + lk * 8);

    float m_[4], l_[4];
    f32x4 o_[4];
#pragma unroll
    for (int j = 0; j < 4; ++j) { m_[j] = -1e30f; l_[j] = 0.f; }
    f32x4 zf = {0.f, 0.f, 0.f, 0.f};
#pragma unroll
    for (int nd = 0; nd < 4; ++nd) o_[nd] = zf;

    for (int t0 = 0; t0 <= q0; t0 += 64) {
        f32x4 s[4];
#pragma unroll
        for (int nf = 0; nf < 4; ++nf) {
            const unsigned short* krow = kbf + ((size_t)(t0 + nf * 16 + lm) * KVH_ + kvh) * HD_;
            bf16x8 k0 = *(const bf16x8*)(krow + lk * 8);
            bf16x8 k1 = *(const bf16x8*)(krow + 32 + lk * 8);
            f32x4 acc = zf;
            acc = __builtin_amdgcn_mfma_f32_16x16x32_bf16(qf[0], k0, acc, 0, 0, 0);
            acc = __builtin_amdgcn_mfma_f32_16x16x32_bf16(qf[1], k1, acc, 0, 0, 0);
            s[nf] = acc;
        }
        if (t0 == q0) {
#pragma unroll
            for (int nf = 0; nf < 4; ++nf)
#pragma unroll
                for (int j = 0; j < 4; ++j) {
                    int key = nf * 16 + lm, qq = w * 16 + lk * 4 + j;
                    if (key > qq) s[nf][j] = -1e30f;
                }
        }
        float p_[4][4];
#pragma unroll
        for (int j = 0; j < 4; ++j) {
            float mx = fmaxf(fmaxf(s[0][j], s[1][j]), fmaxf(s[2][j], s[3][j]));
#pragma unroll
            for (int off = 8; off > 0; off >>= 1) mx = fmaxf(mx, __shfl_xor(mx, off));
            if (mx > m_[j] + 8.f) {
                float rs = __expf(m_[j] - mx);
                m_[j] = mx;
                l_[j] *= rs;
#pragma unroll
                for (int nd = 0; nd < 4; ++nd) o_[nd][j] *= rs;
            }
            float sum = 0.f;
#pragma unroll
            for (int nf = 0; nf < 4; ++nf) {
                float pv = __expf(s[nf][j] - m_[j]);
                p_[nf][j] = pv; sum += pv;
            }
#pragma unroll
            for (int off = 8; off > 0; off >>= 1) sum += __shfl_xor(sum, off);
            l_[j] += sum;
        }
#pragma unroll
        for (int j = 0; j < 4; ++j) {
            int r = lk * 4 + j;
            unsigned lo = pkbf(p_[0][j], p_[1][j]);
            unsigned hi = pkbf(p_[2][j], p_[3][j]);
            int byte = (lm * 8) ^ ((r & 7) << 4);
            *(uint2*)(myP + r * 128 + byte) = make_uint2(lo, hi);
        }
#pragma unroll
        for (int ks = 0; ks < 2; ++ks) {
            int byte = (ks * 64 + lk * 16) ^ ((lm & 7) << 4);
            bf16x8 pA = *(const bf16x8*)(myP + lm * 128 + byte);
#pragma unroll
            for (int nd = 0; nd < 4; ++nd) {
                const unsigned short* vrow = vtb + ((size_t)kvh * HD_ + nd * 16 + lm) * S_ + t0 + ks * 32 + lk * 8;
                bf16x8 vB = *(const bf16x8*)vrow;
                o_[nd] = __builtin_amdgcn_mfma_f32_16x16x32_bf16(pA, vB, o_[nd], 0, 0, 0);
            }
        }
    }
#pragma unroll
    for (int nd = 0; nd < 4; ++nd)
#pragma unroll
        for (int j = 0; j < 4; ++j) {
            int r = lk * 4 + j;
            float val = o_[nd][j] / l_[j];
            size_t oidx = ((size_t)(q0 + w * 16 + r) * NH_ + h) * HD_ + nd * 16 + lm;
            if (ctx) ctx[oidx] = val;
            ctxb[oidx] = f2bf(val);
        }
}

// ---------------- Router (fallback path)
__global__ __launch_bounds__(64) void router_k(const float* __restrict__ x2,
                                               const float* __restrict__ gw,
                                               int* __restrict__ cnt,
                                               int* __restrict__ elist,
                                               int* __restrict__ eslot,
                                               float* __restrict__ wslot)
{
    int n = blockIdx.x, lane = threadIdx.x;
    float part[E_];
#pragma unroll
    for (int e = 0; e < E_; ++e) part[e] = 0.f;
    const float* xr = x2 + (size_t)n * H_;
    for (int j = lane; j < H_; j += 64) {
        float xv = xr[j];
#pragma unroll
        for (int e = 0; e < E_; ++e) part[e] = fmaf(xv, gw[e * H_ + j], part[e]);
    }
#pragma unroll
    for (int e = 0; e < E_; ++e)
#pragma unroll
        for (int off = 32; off > 0; off >>= 1) part[e] += __shfl_xor(part[e], off);
    if (lane == 0) {
        float mx = part[0];
#pragma unroll
        for (int e = 1; e < E_; ++e) mx = fmaxf(mx, part[e]);
        float rw[E_]; float ssum = 0.f;
#pragma unroll
        for (int e = 0; e < E_; ++e) { rw[e] = expf(part[e] - mx); ssum += rw[e]; }
#pragma unroll
        for (int e = 0; e < E_; ++e) rw[e] /= ssum;
        float best = -1.f; int ba = 0, bb = 1;
        for (int a = 0; a < E_; ++a)
            for (int b = a + 1; b < E_; ++b) {
                float scv = rw[a] + rw[b];
                if (scv > best) { best = scv; ba = a; bb = b; }
            }
        float wa = rw[ba], wb = rw[bb], wsum = wa + wb;
        wa /= wsum; wb /= wsum;
        int p = atomicAdd(&cnt[ba], 1);
        elist[ba * S_ + p] = n; eslot[ba * S_ + p] = 2 * n;
        p = atomicAdd(&cnt[bb], 1);
        elist[bb * S_ + p] = n; eslot[bb * S_ + p] = 2 * n + 1;
        wslot[2 * n] = wa; wslot[2 * n + 1] = wb;
    }
}

// ---------------- MoE up (WB path): 128x64, BK=64, single-buffer gload, hoisted addrs.
__global__ __launch_bounds__(256) void moe_up_g(const unsigned short* __restrict__ x2b,
                                                const unsigned short* __restrict__ w1b,
                                                const unsigned short* __restrict__ w3b,
                                                const int* __restrict__ cnt,
                                                const int* __restrict__ elist,
                                                const int* __restrict__ eslot,
                                                unsigned short* __restrict__ hbuf)
{
    int e = blockIdx.z;
    int c = cnt[e];
    int p0 = blockIdx.y * 128;
    if (p0 >= c) return;
    int i0 = blockIdx.x * 64;
    int tid = threadIdx.x;

    __shared__ char As[16384], B1s[8192], B3s[8192];
    __shared__ int rowtokS[128], rowslotS[128];
    if (tid < 128) {
        int p = min(p0 + tid, c - 1);
        rowtokS[tid]  = elist[e * S_ + p];
        rowslotS[tid] = eslot[e * S_ + p];
    }
    __syncthreads();

    int lane = tid & 63, w = tid >> 6, wm = w >> 1, wn = w & 1;
    int lm = lane & 15, lk = lane >> 4;
    int wb16 = (tid & ~63) * 16;
    size_t wbase = (size_t)e * I_ * H_;

    const unsigned short* aSrc[4];
    const unsigned short* b1Src[2];
    const unsigned short* b3Src[2];
#pragma unroll
    for (int it = 0; it < 4; ++it) {
        int g = tid + it * 256, row = g >> 3, kg = g & 7;
        int kgs = kg ^ (row & 7);
        aSrc[it] = x2b + (size_t)rowtokS[row] * H_ + kgs * 8;
    }
#pragma unroll
    for (int it = 0; it < 2; ++it) {
        int g = tid + it * 256, row = g >> 3, kg = g & 7;
        int kgs = kg ^ (row & 7);
        size_t off = wbase + (size_t)(i0 + row) * H_ + kgs * 8;
        b1Src[it] = w1b + off;
        b3Src[it] = w3b + off;
    }

    f32x4 z = {0.f, 0.f, 0.f, 0.f};
    f32x4 acc1[4][2], acc3[4][2];
#pragma unroll
    for (int mf = 0; mf < 4; ++mf)
#pragma unroll
        for (int nf = 0; nf < 2; ++nf) { acc1[mf][nf] = z; acc3[mf][nf] = z; }

    for (int kt = 0; kt < H_ / 64; ++kt) {
        int kb = kt * 64;
#pragma unroll
        for (int it = 0; it < 4; ++it)
            gload16u(aSrc[it] + kb, As, wb16 + it * 4096);
#pragma unroll
        for (int it = 0; it < 2; ++it) {
            gload16u(b1Src[it] + kb, B1s, wb16 + it * 4096);
            gload16u(b3Src[it] + kb, B3s, wb16 + it * 4096);
        }
        vmdrain();
        __syncthreads();
#pragma unroll
        for (int ks = 0; ks < 2; ++ks) {
            bf16x8 af[4];
#pragma unroll
            for (int mf = 0; mf < 4; ++mf) {
                int row = wm * 64 + mf * 16 + lm;
                af[mf] = *(const bf16x8*)(As + row * 128 + ((ks * 64 + lk * 16) ^ ((row & 7) << 4)));
            }
#pragma unroll
            for (int nf = 0; nf < 2; ++nf) {
                int brow = wn * 32 + nf * 16 + lm;
                int bby = brow * 128 + ((ks * 64 + lk * 16) ^ ((brow & 7) << 4));
                bf16x8 b1 = *(const bf16x8*)(B1s + bby);
                bf16x8 b3 = *(const bf16x8*)(B3s + bby);
#pragma unroll
                for (int mf = 0; mf < 4; ++mf) {
                    acc1[mf][nf] = __builtin_amdgcn_mfma_f32_16x16x32_bf16(af[mf], b1, acc1[mf][nf], 0, 0, 0);
                    acc3[mf][nf] = __builtin_amdgcn_mfma_f32_16x16x32_bf16(af[mf], b3, acc3[mf][nf], 0, 0, 0);
                }
            }
        }
        __syncthreads();
    }

#pragma unroll
    for (int mf = 0; mf < 4; ++mf)
#pragma unroll
        for (int nf = 0; nf < 2; ++nf) {
            int coli = i0 + wn * 32 + nf * 16 + lm;
#pragma unroll
            for (int j = 0; j < 4; ++j) {
                int rloc = wm * 64 + mf * 16 + lk * 4 + j;
                if (p0 + rloc < c) {
                    float h1 = acc1[mf][nf][j];
                    float val = h1 / (1.f + __expf(-h1)) * acc3[mf][nf][j];
                    hbuf[(size_t)rowslotS[rloc] * I_ + coli] = f2bf(val);
                }
            }
        }
}

// ---------------- MoE down (WB path): 128x128, BK=64, split-K, single-buffer, hoisted.
__global__ __launch_bounds__(256) void moe_dn_g(const unsigned short* __restrict__ hbuf,
                                                const unsigned short* __restrict__ w2b,
                                                const int* __restrict__ cnt,
                                                const int* __restrict__ eslot,
                                                unsigned short* __restrict__ dbuf)
{
    int e = blockIdx.z >> 2;
    int slice = blockIdx.z & 3;
    int c = cnt[e];
    int p0 = blockIdx.y * 128;
    if (p0 >= c) return;
    int h0 = blockIdx.x * 128;
    int tid = threadIdx.x;
    const int kb0 = slice * (I_ / KSLC);

    __shared__ char As[16384], Bs[16384];
    __shared__ int rowslotS[128];
    if (tid < 128) rowslotS[tid] = eslot[e * S_ + min(p0 + tid, c - 1)];
    __syncthreads();

    int lane = tid & 63, w = tid >> 6, wm = w >> 1, wn = w & 1;
    int lm = lane & 15, lk = lane >> 4;
    int wb16 = (tid & ~63) * 16;
    size_t wbase = (size_t)e * H_ * I_;

    const unsigned short* aSrc[4];
    const unsigned short* bSrc[4];
#pragma unroll
    for (int it = 0; it < 4; ++it) {
        int g = tid + it * 256, row = g >> 3, kg = g & 7;
        int kgs = kg ^ (row & 7);
        aSrc[it] = hbuf + (size_t)rowslotS[row] * I_ + kb0 + kgs * 8;
        bSrc[it] = w2b + wbase + (size_t)(h0 + row) * I_ + kb0 + kgs * 8;
    }

    f32x4 z = {0.f, 0.f, 0.f, 0.f};
    f32x4 acc[4][4];
#pragma unroll
    for (int mf = 0; mf < 4; ++mf)
#pragma unroll
        for (int nf = 0; nf < 4; ++nf) acc[mf][nf] = z;

    const int NKT = (I_ / KSLC) / 64;
    for (int kt = 0; kt < NKT; ++kt) {
        int kb = kt * 64;
#pragma unroll
        for (int it = 0; it < 4; ++it) {
            gload16u(aSrc[it] + kb, As, wb16 + it * 4096);
            gload16u(bSrc[it] + kb, Bs, wb16 + it * 4096);
        }
        vmdrain();
        __syncthreads();
#pragma unroll
        for (int ks = 0; ks < 2; ++ks) {
            bf16x8 af[4];
#pragma unroll
            for (int mf = 0; mf < 4; ++mf) {
                int row = wm * 64 + mf * 16 + lm;
                af[mf] = *(const bf16x8*)(As + row * 128 + ((ks * 64 + lk * 16) ^ ((row & 7) << 4)));
            }
#pragma unroll
            for (int nf = 0; nf < 4; ++nf) {
                int brow = wn * 64 + nf * 16 + lm;
                bf16x8 bf = *(const bf16x8*)(Bs + brow * 128 + ((ks * 64 + lk * 16) ^ ((brow & 7) << 4)));
#pragma unroll
                for (int mf = 0; mf < 4; ++mf)
                    acc[mf][nf] = __builtin_amdgcn_mfma_f32_16x16x32_bf16(af[mf], bf, acc[mf][nf], 0, 0, 0);
            }
        }
        __syncthreads();
    }

    unsigned short* dslice = dbuf + (size_t)slice * S_ * 2 * H_;
#pragma unroll
    for (int mf = 0; mf < 4; ++mf)
#pragma unroll
        for (int nf = 0; nf < 4; ++nf) {
            int colh = h0 + wn * 64 + nf * 16 + lm;
#pragma unroll
            for (int j = 0; j < 4; ++j) {
                int rloc = wm * 64 + mf * 16 + lk * 4 + j;
                if (p0 + rloc < c)
                    dslice[(size_t)rowslotS[rloc] * H_ + colh] = f2bf(acc[mf][nf][j]);
            }
        }
}

// ---------------- MoE up (reg-staged, WB=false fallback)
template<bool WB>
__global__ __launch_bounds__(256) void moe_up_mfma(const float* __restrict__ x2,
                                                   const void* __restrict__ w1,
                                                   const void* __restrict__ w3,
                                                   const int* __restrict__ cnt,
                                                   const int* __restrict__ elist,
                                                   const int* __restrict__ eslot,
                                                   unsigned short* __restrict__ hbuf)
{
    int e = blockIdx.z;
    int c = cnt[e];
    int p0 = blockIdx.y * 128;
    if (p0 >= c) return;
    int i0 = blockIdx.x * 64;
    int tid = threadIdx.x;

    __shared__ char As[16384], B1s[8192], B3s[8192];
    __shared__ int rowtokS[128], rowslotS[128];
    if (tid < 128) {
        int p = min(p0 + tid, c - 1);
        rowtokS[tid]  = elist[e * S_ + p];
        rowslotS[tid] = eslot[e * S_ + p];
    }
    __syncthreads();

    int lane = tid & 63, w = tid >> 6, wm = w >> 1, wn = w & 1;
    int lm = lane & 15, lk = lane >> 4;
    size_t wbase = (size_t)e * I_ * H_;

    int4 rA[4], rB1[2], rB3[2];
    auto loadAll = [&](int kb) {
#pragma unroll
        for (int it = 0; it < 4; ++it) {
            int g = tid + it * 256, row = g >> 3, kg = g & 7;
            const float* s = x2 + (size_t)rowtokS[row] * H_ + kb + kg * 8;
            float4 f0 = *(const float4*)s, f1 = *(const float4*)(s + 4);
            rA[it] = make_int4(pkbf(f0.x, f0.y), pkbf(f0.z, f0.w),
                               pkbf(f1.x, f1.y), pkbf(f1.z, f1.w));
        }
#pragma unroll
        for (int it = 0; it < 2; ++it) {
            int g = tid + it * 256, row = g >> 3, kg = g & 7;
            size_t off = wbase + (size_t)(i0 + row) * H_ + kb + kg * 8;
            rB1[it] = loadW16<WB>(w1, off);
            rB3[it] = loadW16<WB>(w3, off);
        }
    };
    auto writeAll = [&]() {
#pragma unroll
        for (int it = 0; it < 4; ++it) {
            int g = tid + it * 256, row = g >> 3, kg = g & 7;
            int byte = row * 128 + ((kg * 16) ^ ((row & 7) << 4));
            *(int4*)(As + byte) = rA[it];
        }
#pragma unroll
        for (int it = 0; it < 2; ++it) {
            int g = tid + it * 256, row = g >> 3, kg = g & 7;
            int byte = row * 128 + ((kg * 16) ^ ((row & 7) << 4));
            *(int4*)(B1s + byte) = rB1[it];
            *(int4*)(B3s + byte) = rB3[it];
        }
    };

    f32x4 z = {0.f, 0.f, 0.f, 0.f};
    f32x4 acc1[4][2], acc3[4][2];
#pragma unroll
    for (int mf = 0; mf < 4; ++mf)
#pragma unroll
        for (int nf = 0; nf < 2; ++nf) { acc1[mf][nf] = z; acc3[mf][nf] = z; }

    loadAll(0);
    for (int kt = 0; kt < H_ / 64; ++kt) {
        __syncthreads();
        writeAll();
        __syncthreads();
        if (kt + 1 < H_ / 64) loadAll((kt + 1) * 64);
#pragma unroll
        for (int ks = 0; ks < 2; ++ks) {
            bf16x8 af[4];
#pragma unroll
            for (int mf = 0; mf < 4; ++mf) {
                int row = wm * 64 + mf * 16 + lm;
                af[mf] = *(const bf16x8*)(As + row * 128 + ((ks * 64 + lk * 16) ^ ((row & 7) << 4)));
            }
#pragma unroll
            for (int nf = 0; nf < 2; ++nf) {
                int brow = wn * 32 + nf * 16 + lm;
                int bby = brow * 128 + ((ks * 64 + lk * 16) ^ ((brow & 7) << 4));
                bf16x8 b1 = *(const bf16x8*)(B1s + bby);
                bf16x8 b3 = *(const bf16x8*)(B3s + bby);
#pragma unroll
                for (int mf = 0; mf < 4; ++mf) {
                    acc1[mf][nf] = __builtin_amdgcn_mfma_f32_16x16x32_bf16(af[mf], b1, acc1[mf][nf], 0, 0, 0);
                    acc3[mf][nf] = __builtin_amdgcn_mfma_f32_16x16x32_bf16(af[mf], b3, acc3[mf][nf], 0, 0, 0);
                }
            }
        }
    }

#pragma unroll
    for (int mf = 0; mf < 4; ++mf)
#pragma unroll
        for (int nf = 0; nf < 2; ++nf) {
            int coli = i0 + wn * 32 + nf * 16 + lm;
#pragma unroll
            for (int j = 0; j < 4; ++j) {
                int rloc = wm * 64 + mf * 16 + lk * 4 + j;
                if (p0 + rloc < c) {
                    float h1 = acc1[mf][nf][j];
                    float val = h1 / (1.f + __expf(-h1)) * acc3[mf][nf][j];
                    hbuf[(size_t)rowslotS[rloc] * I_ + coli] = f2bf(val);
                }
            }
        }
}

// ---------------- MoE down (reg-staged, WB=false fallback)
template<bool WB>
__global__ __launch_bounds__(256) void moe_dn_mfma(const unsigned short* __restrict__ hbuf,
                                                   const void* __restrict__ w2,
                                                   const int* __restrict__ cnt,
                                                   const int* __restrict__ eslot,
                                                   unsigned short* __restrict__ dbuf)
{
    int e = blockIdx.z >> 2;
    int slice = blockIdx.z & 3;
    int c = cnt[e];
    int p0 = blockIdx.y * 128;
    if (p0 >= c) return;
    int h0 = blockIdx.x * 128;
    int tid = threadIdx.x;
    const int kb0 = slice * (I_ / KSLC);

    __shared__ char As[16384], Bs[16384];
    __shared__ int rowslotS[128];
    if (tid < 128) rowslotS[tid] = eslot[e * S_ + min(p0 + tid, c - 1)];
    __syncthreads();

    int lane = tid & 63, w = tid >> 6, wm = w >> 1, wn = w & 1;
    int lm = lane & 15, lk = lane >> 4;
    size_t wbase = (size_t)e * H_ * I_;

    int4 rA[4], rB[4];
    auto loadAll = [&](int kb) {
#pragma unroll
        for (int it = 0; it < 4; ++it) {
            int g = tid + it * 256, row = g >> 3, kg = g & 7;
            rA[it] = *(const int4*)(hbuf + (size_t)rowslotS[row] * I_ + kb + kg * 8);
            rB[it] = loadW16<WB>(w2, wbase + (size_t)(h0 + row) * I_ + kb + kg * 8);
        }
    };
    auto writeAll = [&]() {
#pragma unroll
        for (int it = 0; it < 4; ++it) {
            int g = tid + it * 256, row = g >> 3, kg = g & 7;
            int byte = row * 128 + ((kg * 16) ^ ((row & 7) << 4));
            *(int4*)(As + byte) = rA[it];
            *(int4*)(Bs + byte) = rB[it];
        }
    };

    f32x4 z = {0.f, 0.f, 0.f, 0.f};
    f32x4 acc[4][4];
#pragma unroll
    for (int mf = 0; mf < 4; ++mf)
#pragma unroll
        for (int nf = 0; nf < 4; ++nf) acc[mf][nf] = z;

    loadAll(kb0);
    const int NKT = (I_ / KSLC) / 64;
    for (int kt = 0; kt < NKT; ++kt) {
        __syncthreads();
        writeAll();
        __syncthreads();
        if (kt + 1 < NKT) loadAll(kb0 + (kt + 1) * 64);
#pragma unroll
        for (int ks = 0; ks < 2; ++ks) {
            bf16x8 af[4];
#pragma unroll
            for (int mf = 0; mf < 4; ++mf) {
                int row = wm * 64 + mf * 16 + lm;
                af[mf] = *(const bf16x8*)(As + row * 128 + ((ks * 64 + lk * 16) ^ ((row & 7) << 4)));
            }
#pragma unroll
            for (int nf = 0; nf < 4; ++nf) {
                int brow = wn * 64 + nf * 16 + lm;
                bf16x8 bf = *(const bf16x8*)(Bs + brow * 128 + ((ks * 64 + lk * 16) ^ ((brow & 7) << 4)));
#pragma unroll
                for (int mf = 0; mf < 4; ++mf)
                    acc[mf][nf] = __builtin_amdgcn_mfma_f32_16x16x32_bf16(af[mf], bf, acc[mf][nf], 0, 0, 0);
            }
        }
    }

    unsigned short* dslice = dbuf + (size_t)slice * S_ * 2 * H_;
#pragma unroll
    for (int mf = 0; mf < 4; ++mf)
#pragma unroll
        for (int nf = 0; nf < 4; ++nf) {
            int colh = h0 + wn * 64 + nf * 16 + lm;
#pragma unroll
            for (int j = 0; j < 4; ++j) {
                int rloc = wm * 64 + mf * 16 + lk * 4 + j;
                if (p0 + rloc < c)
                    dslice[(size_t)rowslotS[rloc] * H_ + colh] = f2bf(acc[mf][nf][j]);
            }
        }
}

// ---------------- Final combine
__global__ __launch_bounds__(256) void combine_k(const float* __restrict__ hid2,
                                                 const unsigned short* __restrict__ dbuf,
                                                 const float* __restrict__ wslot,
                                                 float* __restrict__ out)
{
    int idx = blockIdx.x * 256 + threadIdx.x;
    if (idx >= S_ * H_) return;
    int n = idx >> 10;
    int hcol = idx & (H_ - 1);
    float s0 = 0.f, s1 = 0.f;
#pragma unroll
    for (int sl = 0; sl < KSLC; ++sl) {
        const unsigned short* base = dbuf + (size_t)sl * S_ * 2 * H_;
        s0 += bf2f(base[(size_t)(2 * n)     * H_ + hcol]);
        s1 += bf2f(base[(size_t)(2 * n + 1) * H_ + hcol]);
    }
    out[idx] = hid2[idx] + wslot[2 * n] * s0 + wslot[2 * n + 1] * s1;
}

extern "C" void kernel_launch(void* const* d_in, const int* in_sizes, int n_in,
                              void* d_out, int out_size, void* d_ws, size_t ws_size,
                              hipStream_t stream)
{
    const float* hidden = (const float*)d_in[0];
    const float* ln1    = (const float*)d_in[1];
    const float* ln2    = (const float*)d_in[2];
    const float* wq     = (const float*)d_in[3];
    const float* wk     = (const float*)d_in[4];
    const float* wv     = (const float*)d_in[5];
    const float* wo     = (const float*)d_in[6];
    const float* gw     = (const float*)d_in[7];
    const float* w1     = (const float*)d_in[8];
    const float* w2     = (const float*)d_in[9];
    const float* w3     = (const float*)d_in[10];
    float* out = (float*)d_out;

    char* p = (char*)d_ws;
    auto alignp = [&]() { p = (char*)(((uintptr_t)p + 255) & ~(uintptr_t)255); };
    auto alloc_f = [&](size_t n) { alignp(); float* r = (float*)p; p += n * 4; return r; };
    auto alloc_h = [&](size_t n) { alignp(); unsigned short* r = (unsigned short*)p; p += n * 2; return r; };
    auto alloc_i = [&](size_t n) { alignp(); int* r = (int*)p; p += n * 4; return r; };

    float* xb   = alloc_f((size_t)S_ * H_);
    unsigned short* xbb = alloc_h((size_t)S_ * H_);
    float* q    = alloc_f((size_t)S_ * NH_ * HD_);
    float* kb   = alloc_f((size_t)S_ * KVH_ * HD_);
    float* vb   = alloc_f((size_t)S_ * KVH_ * HD_);
    unsigned short* qkvb = alloc_h((size_t)S_ * 2048);
    float* hid2 = alloc_f((size_t)S_ * H_);
    float* x2   = alloc_f((size_t)S_ * H_);
    unsigned short* x2b  = alloc_h((size_t)S_ * H_);
    unsigned short* ctxb = alloc_h((size_t)S_ * H_);
    unsigned short* hbuf = alloc_h((size_t)S_ * 2 * I_);
    unsigned short* dbuf = alloc_h((size_t)KSLC * S_ * 2 * H_);
    float* wslot= alloc_f((size_t)S_ * 2);
    unsigned short* qbf = alloc_h((size_t)S_ * NH_ * HD_);
    unsigned short* kbf = alloc_h((size_t)S_ * KVH_ * HD_);
    unsigned short* vtb = alloc_h((size_t)KVH_ * HD_ * S_);
    int* cnt   = alloc_i(E_);
    int* elist = alloc_i((size_t)E_ * S_);
    int* eslot = alloc_i((size_t)E_ * S_);
    float* ctx = xb;  // fallback alias

    size_t used = (size_t)(p - (char*)d_ws);
    const size_t nW = (size_t)E_ * I_ * H_;
    size_t wbf_bytes = (3 * nW + (size_t)2048 * H_ + (size_t)H_ * NH_ * HD_) * 2 + 8192;
    bool WB = ws_size > used && (ws_size - used) >= wbf_bytes;

    unsigned short *w1b = nullptr, *w3b = nullptr, *w2b = nullptr;
    unsigned short *wqkvb = nullptr, *wob = nullptr;
    if (WB) {
        w1b = alloc_h(nW); w3b = alloc_h(nW); w2b = alloc_h(nW);
        wqkvb = alloc_h((size_t)2048 * H_);
        wob = alloc_h((size_t)H_ * NH_ * HD_);
    }

    hipMemsetAsync(cnt, 0, E_ * sizeof(int), stream);

    if (WB) {
        conv3<<<3072, 256, 0, stream>>>(w1, w3, w2, w1b, w3b, w2b, (long)(nW / 16));
        conv_qkvo<<<1536, 256, 0, stream>>>(wq, wk, wv, wo, wqkvb, wob);

        rmsnorm_k<<<S_, 256, 0, stream>>>(hidden, ln1, nullptr, xbb);
        dense_g<false><<<dim3(32, 16), 256, 0, stream>>>(xbb, wqkvb, nullptr, qkvb, H_, 2048);
        {
            int tot = S_ * (NH_ + KVH_) * 32;
            rope_conv_b<<<SDIV(tot, 256), 256, 0, stream>>>(qkvb, qbf, kbf);
        }
        v_trans_b<<<dim3(S_ / 64, KVH_), 256, 0, stream>>>(qkvb, vtb);
        attn_mfma<<<dim3(16, NH_, 2), 256, 0, stream>>>(qbf, kbf, vtb, nullptr, ctxb);
        dense_g<true><<<dim3(16, 16), 256, 0, stream>>>(ctxb, wob, hidden, hid2, H_, H_);

        rms2router<<<S_, 256, 0, stream>>>(hid2, ln2, gw, x2b, cnt, elist, eslot, wslot);

        moe_up_g<<<dim3(I_ / 64, S_ / 128, E_), 256, 0, stream>>>(x2b, w1b, w3b, cnt, elist, eslot, hbuf);
        moe_dn_g<<<dim3(H_ / 128, S_ / 128, E_ * KSLC), 256, 0, stream>>>(hbuf, w2b, cnt, eslot, dbuf);
    } else {
        rmsnorm_k<<<S_, 256, 0, stream>>>(hidden, ln1, xb, nullptr);
        dense_mfma<false><<<dim3(8, 16), 256, 0, stream>>>(xb, wq, nullptr, q,  S_, NH_ * HD_, H_);
        dense_mfma<false><<<dim3(4, 16), 256, 0, stream>>>(xb, wk, nullptr, kb, S_, KVH_ * HD_, H_);
        dense_mfma<false><<<dim3(4, 16), 256, 0, stream>>>(xb, wv, nullptr, vb, S_, KVH_ * HD_, H_);
        {
            int tot = S_ * (NH_ + KVH_) * 32;
            rope_conv<<<SDIV(tot, 256), 256, 0, stream>>>(q, kb, qbf, kbf);
        }
        v_trans<<<dim3(S_ / 64, KVH_), 256, 0, stream>>>(vb, vtb);
        attn_mfma<<<dim3(16, NH_, 2), 256, 0, stream>>>(qbf, kbf, vtb, ctx, ctxb);
        dense_mfma<false><<<dim3(8, 16), 256, 0, stream>>>(ctx, wo, hidden, hid2, S_, H_, NH_ * HD_);

        rmsnorm_k<<<S_, 256, 0, stream>>>(hid2, ln2, x2, nullptr);
        router_k<<<S_, 64, 0, stream>>>(x2, gw, cnt, elist, eslot, wslot);

        moe_up_mfma<false><<<dim3(I_ / 64, S_ / 128, E_), 256, 0, stream>>>(x2, w1, w3, cnt, elist, eslot, hbuf);
        moe_dn_mfma<false><<<dim3(H_ / 128, S_ / 128, E_ * KSLC), 256, 0, stream>>>(hbuf, w2, cnt, eslot, dbuf);
    }
    combine_k<<<SDIV(S_ * H_, 256), 256, 0, stream>>>(hid2, dbuf, wslot, out);
}

// Round 17
// 464.937 us; speedup vs baseline: 1.0087x; 1.0087x over previous
//
#include <hip/hip_runtime.h>
#include <hip/hip_bf16.h>
#include <math.h>

constexpr int S_ = 2048, H_ = 1024, NH_ = 16, KVH_ = 8, HD_ = 64;
constexpr int E_ = 8, I_ = 3584;
constexpr int KSLC = 4;
constexpr float EPS_ = 1e-6f;
constexpr float THETA_ = 1000000.0f;

#define SDIV(a,b) (((a)+(b)-1)/(b))

typedef __attribute__((ext_vector_type(8))) short bf16x8;
typedef __attribute__((ext_vector_type(4))) float f32x4;
typedef __attribute__((ext_vector_type(4))) int i32x4;

__device__ inline unsigned pkbf(float a, float b) {
    unsigned r;
    asm("v_cvt_pk_bf16_f32 %0, %1, %2" : "=v"(r) : "v"(a), "v"(b));
    return r;
}
__device__ inline unsigned short f2bf(float f) {
    unsigned u = __float_as_uint(f);
    u += 0x7FFF + ((u >> 16) & 1);
    return (unsigned short)(u >> 16);
}
__device__ inline float bf2f(unsigned short v) {
    return __uint_as_float((unsigned)v << 16);
}

__device__ inline void gload16u(const void* gsrc, char* ldsArr, int uoff) {
    int off = __builtin_amdgcn_readfirstlane(uoff);
    __builtin_amdgcn_global_load_lds(
        (__attribute__((address_space(1))) void*)(gsrc),
        (__attribute__((address_space(3))) void*)(ldsArr + off), 16, 0, 0);
}
__device__ inline void vmdrain() {
    asm volatile("s_waitcnt vmcnt(0)" ::: "memory");
}

template<bool WB>
__device__ inline int4 loadW16(const void* W, size_t elemOff) {
    if constexpr (WB) {
        return *(const int4*)((const unsigned short*)W + elemOff);
    } else {
        const float* s = (const float*)W + elemOff;
        float4 f0 = *(const float4*)s, f1 = *(const float4*)(s + 4);
        return make_int4(pkbf(f0.x, f0.y), pkbf(f0.z, f0.w),
                         pkbf(f1.x, f1.y), pkbf(f1.z, f1.w));
    }
}

// ---------------- merged conv for the 3 big MoE weights:
// NT loads (source is dead after), NORMAL stores (bf16 consumed downstream -> keep in L2/L3).
__global__ __launch_bounds__(256) void conv3(const float* __restrict__ a,
                                             const float* __restrict__ b,
                                             const float* __restrict__ c,
                                             unsigned short* __restrict__ oa,
                                             unsigned short* __restrict__ ob,
                                             unsigned short* __restrict__ oc,
                                             long n16)
{
    int t = blockIdx.y;
    const float* in = (t == 0) ? a : (t == 1) ? b : c;
    unsigned short* out = (t == 0) ? oa : (t == 1) ? ob : oc;
    long stride = (long)gridDim.x * 256;
    for (long v = (long)blockIdx.x * 256 + threadIdx.x; v < n16; v += stride) {
        const float* s = in + v * 16;
        unsigned short* o = out + v * 16;
        f32x4 f0 = __builtin_nontemporal_load((const f32x4*)s);
        f32x4 f1 = __builtin_nontemporal_load((const f32x4*)(s + 4));
        f32x4 f2 = __builtin_nontemporal_load((const f32x4*)(s + 8));
        f32x4 f3 = __builtin_nontemporal_load((const f32x4*)(s + 12));
        i32x4 o0, o1;
        o0.x = (int)pkbf(f0.x, f0.y); o0.y = (int)pkbf(f0.z, f0.w);
        o0.z = (int)pkbf(f1.x, f1.y); o0.w = (int)pkbf(f1.z, f1.w);
        o1.x = (int)pkbf(f2.x, f2.y); o1.y = (int)pkbf(f2.z, f2.w);
        o1.z = (int)pkbf(f3.x, f3.y); o1.w = (int)pkbf(f3.z, f3.w);
        *(i32x4*)o = o0;
        *(i32x4*)(o + 8) = o1;
    }
}

// ---------------- merged conv for wq|wk|wv -> wqkvb and wo -> wob
__global__ __launch_bounds__(256) void conv_qkvo(const float* __restrict__ wq,
                                                 const float* __restrict__ wk,
                                                 const float* __restrict__ wv,
                                                 const float* __restrict__ wo,
                                                 unsigned short* __restrict__ wqkvb,
                                                 unsigned short* __restrict__ wob)
{
    const long NQ = (long)NH_ * HD_ * H_ / 8;      // 131072
    const long NK = (long)KVH_ * HD_ * H_ / 8;     // 65536
    long u = (long)blockIdx.x * 256 + threadIdx.x; // grid sized exactly
    const float* in; unsigned short* out;
    if (u < NQ)                { in = wq + u * 8;               out = wqkvb + u * 8; }
    else if (u < NQ + NK)      { long v = u - NQ;      in = wk + v * 8; out = wqkvb + (NQ + v) * 8; }
    else if (u < NQ + 2 * NK)  { long v = u - NQ - NK; in = wv + v * 8; out = wqkvb + (NQ + NK + v) * 8; }
    else                       { long v = u - NQ - 2 * NK; in = wo + v * 8; out = wob + v * 8; }
    float4 f0 = *(const float4*)in, f1 = *(const float4*)(in + 4);
    *(int4*)out = make_int4(pkbf(f0.x, f0.y), pkbf(f0.z, f0.w),
                            pkbf(f1.x, f1.y), pkbf(f1.z, f1.w));
}

// ---------------- RMSNorm (fp32 out and bf16 out both optional)
__global__ __launch_bounds__(256) void rmsnorm_k(const float* __restrict__ x,
                                                 const float* __restrict__ w,
                                                 float* __restrict__ out,
                                                 unsigned short* __restrict__ outb)
{
    int row = blockIdx.x;
    int tid = threadIdx.x;
    const float* xr = x + (size_t)row * H_;
    float4 v = *(const float4*)&xr[tid * 4];
    float ss = v.x*v.x + v.y*v.y + v.z*v.z + v.w*v.w;
#pragma unroll
    for (int off = 32; off > 0; off >>= 1) ss += __shfl_xor(ss, off);
    __shared__ float red[4];
    if ((tid & 63) == 0) red[tid >> 6] = ss;
    __syncthreads();
    float tot = red[0] + red[1] + red[2] + red[3];
    float r = rsqrtf(tot / (float)H_ + EPS_);
    float4 wv = *(const float4*)&w[tid * 4];
    float4 o;
    o.x = v.x * r * wv.x; o.y = v.y * r * wv.y;
    o.z = v.z * r * wv.z; o.w = v.w * r * wv.w;
    if (out) *(float4*)&out[(size_t)row * H_ + tid * 4] = o;
    if (outb) {
        uint2 pk = make_uint2(pkbf(o.x, o.y), pkbf(o.z, o.w));
        *(uint2*)&outb[(size_t)row * H_ + tid * 4] = pk;
    }
}

// ---------------- Fused RMSNorm2 + router (WB path)
__global__ __launch_bounds__(256) void rms2router(const float* __restrict__ x,
                                                  const float* __restrict__ w,
                                                  const float* __restrict__ gw,
                                                  unsigned short* __restrict__ outb,
                                                  int* __restrict__ cnt,
                                                  int* __restrict__ elist,
                                                  int* __restrict__ eslot,
                                                  float* __restrict__ wslot)
{
    int row = blockIdx.x;
    int tid = threadIdx.x;
    const float* xr = x + (size_t)row * H_;
    float4 v = *(const float4*)&xr[tid * 4];
    float ss = v.x*v.x + v.y*v.y + v.z*v.z + v.w*v.w;
#pragma unroll
    for (int off = 32; off > 0; off >>= 1) ss += __shfl_xor(ss, off);
    __shared__ float red[4];
    __shared__ float redE[4][8];
    if ((tid & 63) == 0) red[tid >> 6] = ss;
    __syncthreads();
    float tot = red[0] + red[1] + red[2] + red[3];
    float r = rsqrtf(tot / (float)H_ + EPS_);
    float4 wv = *(const float4*)&w[tid * 4];
    float o0 = v.x * r * wv.x, o1 = v.y * r * wv.y;
    float o2 = v.z * r * wv.z, o3 = v.w * r * wv.w;
    uint2 pk = make_uint2(pkbf(o0, o1), pkbf(o2, o3));
    *(uint2*)&outb[(size_t)row * H_ + tid * 4] = pk;

    int col = tid * 4;
    float part[E_];
#pragma unroll
    for (int e = 0; e < E_; ++e) {
        const float* g = gw + (size_t)e * H_ + col;
        part[e] = o0 * g[0] + o1 * g[1] + o2 * g[2] + o3 * g[3];
    }
#pragma unroll
    for (int e = 0; e < E_; ++e)
#pragma unroll
        for (int off = 32; off > 0; off >>= 1) part[e] += __shfl_xor(part[e], off);
    if ((tid & 63) == 0)
#pragma unroll
        for (int e = 0; e < E_; ++e) redE[tid >> 6][e] = part[e];
    __syncthreads();
    if (tid == 0) {
        float lg[E_];
#pragma unroll
        for (int e = 0; e < E_; ++e)
            lg[e] = redE[0][e] + redE[1][e] + redE[2][e] + redE[3][e];
        float mx = lg[0];
#pragma unroll
        for (int e = 1; e < E_; ++e) mx = fmaxf(mx, lg[e]);
        float rw[E_]; float ssum = 0.f;
#pragma unroll
        for (int e = 0; e < E_; ++e) { rw[e] = expf(lg[e] - mx); ssum += rw[e]; }
#pragma unroll
        for (int e = 0; e < E_; ++e) rw[e] /= ssum;
        float best = -1.f; int ba = 0, bb = 1;
        for (int a = 0; a < E_; ++a)
            for (int b = a + 1; b < E_; ++b) {
                float scv = rw[a] + rw[b];
                if (scv > best) { best = scv; ba = a; bb = b; }
            }
        float wa = rw[ba], wb = rw[bb], wsum = wa + wb;
        wa /= wsum; wb /= wsum;
        int n = row;
        int p = atomicAdd(&cnt[ba], 1);
        elist[ba * S_ + p] = n; eslot[ba * S_ + p] = 2 * n;
        p = atomicAdd(&cnt[bb], 1);
        elist[bb * S_ + p] = n; eslot[bb * S_ + p] = 2 * n + 1;
        wslot[2 * n] = wa; wslot[2 * n + 1] = wb;
    }
}

// ---------------- Dense g-style GEMM (WB path): 128(M) x 64(N), BK=64. Hoisted addrs.
template<bool OUTF32>
__global__ __launch_bounds__(256) void dense_g(const unsigned short* __restrict__ A,
                                               const unsigned short* __restrict__ B,
                                               const float* __restrict__ Res,
                                               void* __restrict__ C,
                                               int K, int ldC)
{
    int m0 = blockIdx.y * 128, n0 = blockIdx.x * 64;
    int tid = threadIdx.x;
    __shared__ char As[16384], Bs[8192];
    int lane = tid & 63, w = tid >> 6, wm = w >> 1, wn = w & 1;
    int lm = lane & 15, lk = lane >> 4;
    int wb16 = (tid & ~63) * 16;

    const unsigned short* aSrc[4];
    const unsigned short* bSrc[2];
#pragma unroll
    for (int it = 0; it < 4; ++it) {
        int g = tid + it * 256, row = g >> 3, kg = g & 7;
        int kgs = kg ^ (row & 7);
        aSrc[it] = A + (size_t)(m0 + row) * K + kgs * 8;
    }
#pragma unroll
    for (int it = 0; it < 2; ++it) {
        int g = tid + it * 256, row = g >> 3, kg = g & 7;
        int kgs = kg ^ (row & 7);
        bSrc[it] = B + (size_t)(n0 + row) * K + kgs * 8;
    }

    f32x4 z = {0.f, 0.f, 0.f, 0.f};
    f32x4 acc[4][2];
#pragma unroll
    for (int mf = 0; mf < 4; ++mf)
#pragma unroll
        for (int nf = 0; nf < 2; ++nf) acc[mf][nf] = z;

    for (int kt = 0; kt < K / 64; ++kt) {
        int kb = kt * 64;
#pragma unroll
        for (int it = 0; it < 4; ++it)
            gload16u(aSrc[it] + kb, As, wb16 + it * 4096);
#pragma unroll
        for (int it = 0; it < 2; ++it)
            gload16u(bSrc[it] + kb, Bs, wb16 + it * 4096);
        vmdrain();
        __syncthreads();
#pragma unroll
        for (int ks = 0; ks < 2; ++ks) {
            bf16x8 af[4];
#pragma unroll
            for (int mf = 0; mf < 4; ++mf) {
                int row = wm * 64 + mf * 16 + lm;
                af[mf] = *(const bf16x8*)(As + row * 128 + ((ks * 64 + lk * 16) ^ ((row & 7) << 4)));
            }
#pragma unroll
            for (int nf = 0; nf < 2; ++nf) {
                int brow = wn * 32 + nf * 16 + lm;
                bf16x8 bf = *(const bf16x8*)(Bs + brow * 128 + ((ks * 64 + lk * 16) ^ ((brow & 7) << 4)));
#pragma unroll
                for (int mf = 0; mf < 4; ++mf)
                    acc[mf][nf] = __builtin_amdgcn_mfma_f32_16x16x32_bf16(af[mf], bf, acc[mf][nf], 0, 0, 0);
            }
        }
        __syncthreads();
    }

#pragma unroll
    for (int mf = 0; mf < 4; ++mf)
#pragma unroll
        for (int nf = 0; nf < 2; ++nf) {
            int col = n0 + wn * 32 + nf * 16 + lm;
#pragma unroll
            for (int j = 0; j < 4; ++j) {
                int row = m0 + wm * 64 + mf * 16 + lk * 4 + j;
                float v = acc[mf][nf][j];
                if constexpr (OUTF32) {
                    float r = Res ? Res[(size_t)row * ldC + col] : 0.0f;
                    ((float*)C)[(size_t)row * ldC + col] = v + r;
                } else {
                    ((unsigned short*)C)[(size_t)row * ldC + col] = f2bf(v);
                }
            }
        }
}

// ---------------- Dense bf16-MFMA GEMM (reg-staged; WB=false fallback)
template<bool WB>
__global__ __launch_bounds__(256) void dense_mfma(const float* __restrict__ A,
                                                  const void* __restrict__ Bw,
                                                  const float* __restrict__ Res,
                                                  float* __restrict__ C,
                                                  int M, int N, int K)
{
    __shared__ char As[16384], Bs[16384];
    int tid = threadIdx.x;
    int m0 = blockIdx.y * 128, n0 = blockIdx.x * 128;
    int lane = tid & 63, w = tid >> 6, wm = w >> 1, wn = w & 1;
    int lm = lane & 15, lk = lane >> 4;

    int4 rA[4], rB[4];
    auto loadAll = [&](int kb) {
#pragma unroll
        for (int it = 0; it < 4; ++it) {
            int g = tid + it * 256, row = g >> 3, kg = g & 7;
            const float* s = A + (size_t)(m0 + row) * K + kb + kg * 8;
            float4 f0 = *(const float4*)s, f1 = *(const float4*)(s + 4);
            rA[it] = make_int4(pkbf(f0.x, f0.y), pkbf(f0.z, f0.w),
                               pkbf(f1.x, f1.y), pkbf(f1.z, f1.w));
            rB[it] = loadW16<WB>(Bw, (size_t)(n0 + row) * K + kb + kg * 8);
        }
    };
    auto writeAll = [&]() {
#pragma unroll
        for (int it = 0; it < 4; ++it) {
            int g = tid + it * 256, row = g >> 3, kg = g & 7;
            int byte = row * 128 + ((kg * 16) ^ ((row & 7) << 4));
            *(int4*)(As + byte) = rA[it];
            *(int4*)(Bs + byte) = rB[it];
        }
    };

    f32x4 z = {0.f, 0.f, 0.f, 0.f};
    f32x4 acc[4][4];
#pragma unroll
    for (int mf = 0; mf < 4; ++mf)
#pragma unroll
        for (int nf = 0; nf < 4; ++nf) acc[mf][nf] = z;

    loadAll(0);
    for (int kt = 0; kt < K / 64; ++kt) {
        __syncthreads();
        writeAll();
        __syncthreads();
        if (kt + 1 < K / 64) loadAll((kt + 1) * 64);
#pragma unroll
        for (int ks = 0; ks < 2; ++ks) {
            bf16x8 af[4];
#pragma unroll
            for (int mf = 0; mf < 4; ++mf) {
                int row = wm * 64 + mf * 16 + lm;
                af[mf] = *(const bf16x8*)(As + row * 128 + ((ks * 64 + lk * 16) ^ ((row & 7) << 4)));
            }
#pragma unroll
            for (int nf = 0; nf < 4; ++nf) {
                int brow = wn * 64 + nf * 16 + lm;
                bf16x8 bf = *(const bf16x8*)(Bs + brow * 128 + ((ks * 64 + lk * 16) ^ ((brow & 7) << 4)));
#pragma unroll
                for (int mf = 0; mf < 4; ++mf)
                    acc[mf][nf] = __builtin_amdgcn_mfma_f32_16x16x32_bf16(af[mf], bf, acc[mf][nf], 0, 0, 0);
            }
        }
    }

#pragma unroll
    for (int mf = 0; mf < 4; ++mf)
#pragma unroll
        for (int nf = 0; nf < 4; ++nf) {
            int col = n0 + wn * 64 + nf * 16 + lm;
#pragma unroll
            for (int j = 0; j < 4; ++j) {
                int row = m0 + wm * 64 + mf * 16 + lk * 4 + j;
                float r = Res ? Res[(size_t)row * N + col] : 0.0f;
                C[(size_t)row * N + col] = acc[mf][nf][j] + r;
            }
        }
}

// ---------------- RoPE + bf16 (WB path): reads fused bf16 qkvb [S][2048]
__global__ __launch_bounds__(256) void rope_conv_b(const unsigned short* __restrict__ qkvb,
                                                   unsigned short* __restrict__ qbf,
                                                   unsigned short* __restrict__ kbf)
{
    int idx = blockIdx.x * 256 + threadIdx.x;
    const int totq = S_ * NH_ * 32;
    const int tot = totq + S_ * KVH_ * 32;
    if (idx >= tot) return;
    const unsigned short* src; unsigned short* dst; int s, di; float sc;
    if (idx < totq) {
        s = idx / (NH_ * 32); int r = idx % (NH_ * 32); int h = r >> 5;
        src = qkvb + (size_t)s * 2048 + h * 64;
        dst = qbf + ((size_t)s * NH_ + h) * HD_;
        di = r & 31; sc = 0.125f;
    } else {
        int j2 = idx - totq;
        s = j2 / (KVH_ * 32); int r = j2 % (KVH_ * 32); int kvh = r >> 5;
        src = qkvb + (size_t)s * 2048 + 1024 + kvh * 64;
        dst = kbf + ((size_t)s * KVH_ + kvh) * HD_;
        di = r & 31; sc = 1.0f;
    }
    float invf = powf(THETA_, -(2.0f * di) / (float)HD_);
    float ang = (float)s * invf;
    float c = cosf(ang), sn = sinf(ang);
    float x0 = bf2f(src[di]), x1 = bf2f(src[di + 32]);
    dst[di]      = f2bf((x0 * c - x1 * sn) * sc);
    dst[di + 32] = f2bf((x1 * c + x0 * sn) * sc);
}

// ---------------- V transpose (WB path): V from qkvb cols [1536..2048)
__global__ __launch_bounds__(256) void v_trans_b(const unsigned short* __restrict__ qkvb,
                                                 unsigned short* __restrict__ vtb)
{
    int t0 = blockIdx.x * 64, kvh = blockIdx.y;
    __shared__ unsigned short T[64][64];
    int tid = threadIdx.x;
    int k = tid >> 2, d0 = (tid & 3) * 16;
    const unsigned short* src = qkvb + (size_t)(t0 + k) * 2048 + 1536 + kvh * 64 + d0;
    *(int4*)&T[k][d0]     = *(const int4*)(src);
    *(int4*)&T[k][d0 + 8] = *(const int4*)(src + 8);
    __syncthreads();
    int d = tid >> 2, s0 = (tid & 3) * 16;
    unsigned short tmp[16] __attribute__((aligned(16)));
#pragma unroll
    for (int x = 0; x < 16; ++x) {
        int s = s0 + x;
        int key = 16 * (s & 3) + (s >> 2);
        tmp[x] = T[key][d];
    }
    unsigned short* dst = vtb + ((size_t)kvh * HD_ + d) * S_ + t0 + s0;
    *(int4*)(dst)     = *(int4*)(tmp);
    *(int4*)(dst + 8) = *(int4*)(tmp + 8);
}

// ---------------- RoPE + bf16 convert (fallback: fp32 q/k inputs)
__global__ __launch_bounds__(256) void rope_conv(const float* __restrict__ q,
                                                 const float* __restrict__ k,
                                                 unsigned short* __restrict__ qbf,
                                                 unsigned short* __restrict__ kbf)
{
    int idx = blockIdx.x * 256 + threadIdx.x;
    const int totq = S_ * NH_ * 32;
    const int tot = totq + S_ * KVH_ * 32;
    if (idx >= tot) return;
    const float* base; unsigned short* obase; int s, di; float sc;
    if (idx < totq) {
        s = idx / (NH_ * 32); int r = idx % (NH_ * 32);
        size_t o = ((size_t)s * NH_ + (r >> 5)) * HD_;
        base = q + o; obase = qbf + o; di = r & 31; sc = 0.125f;
    } else {
        int j2 = idx - totq;
        s = j2 / (KVH_ * 32); int r = j2 % (KVH_ * 32);
        size_t o = ((size_t)s * KVH_ + (r >> 5)) * HD_;
        base = k + o; obase = kbf + o; di = r & 31; sc = 1.0f;
    }
    float invf = powf(THETA_, -(2.0f * di) / (float)HD_);
    float ang = (float)s * invf;
    float c = cosf(ang), sn = sinf(ang);
    float x0 = base[di], x1 = base[di + 32];
    obase[di]      = f2bf((x0 * c - x1 * sn) * sc);
    obase[di + 32] = f2bf((x1 * c + x0 * sn) * sc);
}

// ---------------- V transpose (fallback: fp32 V input)
__global__ __launch_bounds__(256) void v_trans(const float* __restrict__ v,
                                               unsigned short* __restrict__ vtb)
{
    int t0 = blockIdx.x * 64, kvh = blockIdx.y;
    __shared__ unsigned short T[64][64];
    int tid = threadIdx.x;
    int k = tid >> 2, d0 = (tid & 3) * 16;
    const float* src = v + ((size_t)(t0 + k) * KVH_ + kvh) * HD_ + d0;
#pragma unroll
    for (int x = 0; x < 4; ++x) {
        float4 f = *(const float4*)(src + x * 4);
        T[k][d0 + x*4 + 0] = f2bf(f.x);
        T[k][d0 + x*4 + 1] = f2bf(f.y);
        T[k][d0 + x*4 + 2] = f2bf(f.z);
        T[k][d0 + x*4 + 3] = f2bf(f.w);
    }
    __syncthreads();
    int d = tid >> 2, s0 = (tid & 3) * 16;
    unsigned short tmp[16] __attribute__((aligned(16)));
#pragma unroll
    for (int x = 0; x < 16; ++x) {
        int s = s0 + x;
        int key = 16 * (s & 3) + (s >> 2);
        tmp[x] = T[key][d];
    }
    unsigned short* dst = vtb + ((size_t)kvh * HD_ + d) * S_ + t0 + s0;
    *(int4*)(dst)     = *(int4*)(tmp);
    *(int4*)(dst + 8) = *(int4*)(tmp + 8);
}

// ---------------- MFMA flash attention (fp32 ctx optional; defer-max softmax)
__global__ __launch_bounds__(256) void attn_mfma(const unsigned short* __restrict__ qbf,
                                                 const unsigned short* __restrict__ kbf,
                                                 const unsigned short* __restrict__ vtb,
                                                 float* __restrict__ ctx,
                                                 unsigned short* __restrict__ ctxb)
{
    __shared__ char Ps[4 * 2048];
    int pair = blockIdx.x, h = blockIdx.y, z = blockIdx.z;
    int qb = z ? (31 - pair) : pair;
    int q0 = qb * 64;
    int kvh = h >> 1;
    int tid = threadIdx.x;
    int w = tid >> 6, lane = tid & 63;
    int lm = lane & 15, lk = lane >> 4;
    char* myP = Ps + w * 2048;

    bf16x8 qf[2];
    const unsigned short* qrow = qbf + ((size_t)(q0 + w * 16 + lm) * NH_ + h) * HD_;
#pragma unroll
    for (int ks = 0; ks < 2; ++ks)
        qf[ks] = *(const bf16x8*)(qrow + ks * 32 + lk * 8);

    float m_[4], l_[4];
    f32x4 o_[4];
#pragma unroll
    for (int j = 0; j < 4; ++j) { m_[j] = -1e30f; l_[j] = 0.f; }
    f32x4 zf = {0.f, 0.f, 0.f, 0.f};
#pragma unroll
    for (int nd = 0; nd < 4; ++nd) o_[nd] = zf;

    for (int t0 = 0; t0 <= q0; t0 += 64) {
        f32x4 s[4];
#pragma unroll
        for (int nf = 0; nf < 4; ++nf) {
            const unsigned short* krow = kbf + ((size_t)(t0 + nf * 16 + lm) * KVH_ + kvh) * HD_;
            bf16x8 k0 = *(const bf16x8*)(krow + lk * 8);
            bf16x8 k1 = *(const bf16x8*)(krow + 32 + lk * 8);
            f32x4 acc = zf;
            acc = __builtin_amdgcn_mfma_f32_16x16x32_bf16(qf[0], k0, acc, 0, 0, 0);
            acc = __builtin_amdgcn_mfma_f32_16x16x32_bf16(qf[1], k1, acc, 0, 0, 0);
            s[nf] = acc;
        }
        if (t0 == q0) {
#pragma unroll
            for (int nf = 0; nf < 4; ++nf)
#pragma unroll
                for (int j = 0; j < 4; ++j) {
                    int key = nf * 16 + lm, qq = w * 16 + lk * 4 + j;
                    if (key > qq) s[nf][j] = -1e30f;
                }
        }
        float p_[4][4];
#pragma unroll
        for (int j = 0; j < 4; ++j) {
            float mx = fmaxf(fmaxf(s[0][j], s[1][j]), fmaxf(s[2][j], s[3][j]));
#pragma unroll
            for (int off = 8; off > 0; off >>= 1) mx = fmaxf(mx, __shfl_xor(mx, off));
            if (mx > m_[j] + 8.f) {
                float rs = __expf(m_[j] - mx);
                m_[j] = mx;
                l_[j] *= rs;
#pragma unroll
                for (int nd = 0; nd < 4; ++nd) o_[nd][j] *= rs;
            }
            float sum = 0.f;
#pragma unroll
            for (int nf = 0; nf < 4; ++nf) {
                float pv = __expf(s[nf][j] - m_[j]);
                p_[nf][j] = pv; sum += pv;
            }
#pragma unroll
            for (int off = 8; off > 0; off >>= 1) sum += __shfl_xor(sum, off);
            l_[j] += sum;
        }
#pragma unroll
        for (int j = 0; j < 4; ++j) {
            int r = lk * 4 + j;
            unsigned lo = pkbf(p_[0][j], p_[1][j]);
            unsigned hi = pkbf(p_[2][j], p_[3][j]);
            int byte = (lm * 8) ^ ((r & 7) << 4);
            *(uint2*)(myP + r * 128 + byte) = make_uint2(lo, hi);
        }
#pragma unroll
        for (int ks = 0; ks < 2; ++ks) {
            int byte = (ks * 64 + lk * 16) ^ ((lm & 7) << 4);
            bf16x8 pA = *(const bf16x8*)(myP + lm * 128 + byte);
#pragma unroll
            for (int nd = 0; nd < 4; ++nd) {
                const unsigned short* vrow = vtb + ((size_t)kvh * HD_ + nd * 16 + lm) * S_ + t0 + ks * 32 + lk * 8;
                bf16x8 vB = *(const bf16x8*)vrow;
                o_[nd] = __builtin_amdgcn_mfma_f32_16x16x32_bf16(pA, vB, o_[nd], 0, 0, 0);
            }
        }
    }
#pragma unroll
    for (int nd = 0; nd < 4; ++nd)
#pragma unroll
        for (int j = 0; j < 4; ++j) {
            int r = lk * 4 + j;
            float val = o_[nd][j] / l_[j];
            size_t oidx = ((size_t)(q0 + w * 16 + r) * NH_ + h) * HD_ + nd * 16 + lm;
            if (ctx) ctx[oidx] = val;
            ctxb[oidx] = f2bf(val);
        }
}

// ---------------- Router (fallback path)
__global__ __launch_bounds__(64) void router_k(const float* __restrict__ x2,
                                               const float* __restrict__ gw,
                                               int* __restrict__ cnt,
                                               int* __restrict__ elist,
                                               int* __restrict__ eslot,
                                               float* __restrict__ wslot)
{
    int n = blockIdx.x, lane = threadIdx.x;
    float part[E_];
#pragma unroll
    for (int e = 0; e < E_; ++e) part[e] = 0.f;
    const float* xr = x2 + (size_t)n * H_;
    for (int j = lane; j < H_; j += 64) {
        float xv = xr[j];
#pragma unroll
        for (int e = 0; e < E_; ++e) part[e] = fmaf(xv, gw[e * H_ + j], part[e]);
    }
#pragma unroll
    for (int e = 0; e < E_; ++e)
#pragma unroll
        for (int off = 32; off > 0; off >>= 1) part[e] += __shfl_xor(part[e], off);
    if (lane == 0) {
        float mx = part[0];
#pragma unroll
        for (int e = 1; e < E_; ++e) mx = fmaxf(mx, part[e]);
        float rw[E_]; float ssum = 0.f;
#pragma unroll
        for (int e = 0; e < E_; ++e) { rw[e] = expf(part[e] - mx); ssum += rw[e]; }
#pragma unroll
        for (int e = 0; e < E_; ++e) rw[e] /= ssum;
        float best = -1.f; int ba = 0, bb = 1;
        for (int a = 0; a < E_; ++a)
            for (int b = a + 1; b < E_; ++b) {
                float scv = rw[a] + rw[b];
                if (scv > best) { best = scv; ba = a; bb = b; }
            }
        float wa = rw[ba], wb = rw[bb], wsum = wa + wb;
        wa /= wsum; wb /= wsum;
        int p = atomicAdd(&cnt[ba], 1);
        elist[ba * S_ + p] = n; eslot[ba * S_ + p] = 2 * n;
        p = atomicAdd(&cnt[bb], 1);
        elist[bb * S_ + p] = n; eslot[bb * S_ + p] = 2 * n + 1;
        wslot[2 * n] = wa; wslot[2 * n + 1] = wb;
    }
}

// ---------------- MoE up (WB path): 128x64, BK=64, single-buffer gload, hoisted addrs.
__global__ __launch_bounds__(256) void moe_up_g(const unsigned short* __restrict__ x2b,
                                                const unsigned short* __restrict__ w1b,
                                                const unsigned short* __restrict__ w3b,
                                                const int* __restrict__ cnt,
                                                const int* __restrict__ elist,
                                                const int* __restrict__ eslot,
                                                unsigned short* __restrict__ hbuf)
{
    int e = blockIdx.z;
    int c = cnt[e];
    int p0 = blockIdx.y * 128;
    if (p0 >= c) return;
    int i0 = blockIdx.x * 64;
    int tid = threadIdx.x;

    __shared__ char As[16384], B1s[8192], B3s[8192];
    __shared__ int rowtokS[128], rowslotS[128];
    if (tid < 128) {
        int p = min(p0 + tid, c - 1);
        rowtokS[tid]  = elist[e * S_ + p];
        rowslotS[tid] = eslot[e * S_ + p];
    }
    __syncthreads();

    int lane = tid & 63, w = tid >> 6, wm = w >> 1, wn = w & 1;
    int lm = lane & 15, lk = lane >> 4;
    int wb16 = (tid & ~63) * 16;
    size_t wbase = (size_t)e * I_ * H_;

    const unsigned short* aSrc[4];
    const unsigned short* b1Src[2];
    const unsigned short* b3Src[2];
#pragma unroll
    for (int it = 0; it < 4; ++it) {
        int g = tid + it * 256, row = g >> 3, kg = g & 7;
        int kgs = kg ^ (row & 7);
        aSrc[it] = x2b + (size_t)rowtokS[row] * H_ + kgs * 8;
    }
#pragma unroll
    for (int it = 0; it < 2; ++it) {
        int g = tid + it * 256, row = g >> 3, kg = g & 7;
        int kgs = kg ^ (row & 7);
        size_t off = wbase + (size_t)(i0 + row) * H_ + kgs * 8;
        b1Src[it] = w1b + off;
        b3Src[it] = w3b + off;
    }

    f32x4 z = {0.f, 0.f, 0.f, 0.f};
    f32x4 acc1[4][2], acc3[4][2];
#pragma unroll
    for (int mf = 0; mf < 4; ++mf)
#pragma unroll
        for (int nf = 0; nf < 2; ++nf) { acc1[mf][nf] = z; acc3[mf][nf] = z; }

    for (int kt = 0; kt < H_ / 64; ++kt) {
        int kb = kt * 64;
#pragma unroll
        for (int it = 0; it < 4; ++it)
            gload16u(aSrc[it] + kb, As, wb16 + it * 4096);
#pragma unroll
        for (int it = 0; it < 2; ++it) {
            gload16u(b1Src[it] + kb, B1s, wb16 + it * 4096);
            gload16u(b3Src[it] + kb, B3s, wb16 + it * 4096);
        }
        vmdrain();
        __syncthreads();
#pragma unroll
        for (int ks = 0; ks < 2; ++ks) {
            bf16x8 af[4];
#pragma unroll
            for (int mf = 0; mf < 4; ++mf) {
                int row = wm * 64 + mf * 16 + lm;
                af[mf] = *(const bf16x8*)(As + row * 128 + ((ks * 64 + lk * 16) ^ ((row & 7) << 4)));
            }
#pragma unroll
            for (int nf = 0; nf < 2; ++nf) {
                int brow = wn * 32 + nf * 16 + lm;
                int bby = brow * 128 + ((ks * 64 + lk * 16) ^ ((brow & 7) << 4));
                bf16x8 b1 = *(const bf16x8*)(B1s + bby);
                bf16x8 b3 = *(const bf16x8*)(B3s + bby);
#pragma unroll
                for (int mf = 0; mf < 4; ++mf) {
                    acc1[mf][nf] = __builtin_amdgcn_mfma_f32_16x16x32_bf16(af[mf], b1, acc1[mf][nf], 0, 0, 0);
                    acc3[mf][nf] = __builtin_amdgcn_mfma_f32_16x16x32_bf16(af[mf], b3, acc3[mf][nf], 0, 0, 0);
                }
            }
        }
        __syncthreads();
    }

#pragma unroll
    for (int mf = 0; mf < 4; ++mf)
#pragma unroll
        for (int nf = 0; nf < 2; ++nf) {
            int coli = i0 + wn * 32 + nf * 16 + lm;
#pragma unroll
            for (int j = 0; j < 4; ++j) {
                int rloc = wm * 64 + mf * 16 + lk * 4 + j;
                if (p0 + rloc < c) {
                    float h1 = acc1[mf][nf][j];
                    float val = h1 / (1.f + __expf(-h1)) * acc3[mf][nf][j];
                    hbuf[(size_t)rowslotS[rloc] * I_ + coli] = f2bf(val);
                }
            }
        }
}

// ---------------- MoE down (WB path): 128x128, BK=64, split-K, single-buffer, hoisted.
__global__ __launch_bounds__(256) void moe_dn_g(const unsigned short* __restrict__ hbuf,
                                                const unsigned short* __restrict__ w2b,
                                                const int* __restrict__ cnt,
                                                const int* __restrict__ eslot,
                                                unsigned short* __restrict__ dbuf)
{
    int e = blockIdx.z >> 2;
    int slice = blockIdx.z & 3;
    int c = cnt[e];
    int p0 = blockIdx.y * 128;
    if (p0 >= c) return;
    int h0 = blockIdx.x * 128;
    int tid = threadIdx.x;
    const int kb0 = slice * (I_ / KSLC);

    __shared__ char As[16384], Bs[16384];
    __shared__ int rowslotS[128];
    if (tid < 128) rowslotS[tid] = eslot[e * S_ + min(p0 + tid, c - 1)];
    __syncthreads();

    int lane = tid & 63, w = tid >> 6, wm = w >> 1, wn = w & 1;
    int lm = lane & 15, lk = lane >> 4;
    int wb16 = (tid & ~63) * 16;
    size_t wbase = (size_t)e * H_ * I_;

    const unsigned short* aSrc[4];
    const unsigned short* bSrc[4];
#pragma unroll
    for (int it = 0; it < 4; ++it) {
        int g = tid + it * 256, row = g >> 3, kg = g & 7;
        int kgs = kg ^ (row & 7);
        aSrc[it] = hbuf + (size_t)rowslotS[row] * I_ + kb0 + kgs * 8;
        bSrc[it] = w2b + wbase + (size_t)(h0 + row) * I_ + kb0 + kgs * 8;
    }

    f32x4 z = {0.f, 0.f, 0.f, 0.f};
    f32x4 acc[4][4];
#pragma unroll
    for (int mf = 0; mf < 4; ++mf)
#pragma unroll
        for (int nf = 0; nf < 4; ++nf) acc[mf][nf] = z;

    const int NKT = (I_ / KSLC) / 64;
    for (int kt = 0; kt < NKT; ++kt) {
        int kb = kt * 64;
#pragma unroll
        for (int it = 0; it < 4; ++it) {
            gload16u(aSrc[it] + kb, As, wb16 + it * 4096);
            gload16u(bSrc[it] + kb, Bs, wb16 + it * 4096);
        }
        vmdrain();
        __syncthreads();
#pragma unroll
        for (int ks = 0; ks < 2; ++ks) {
            bf16x8 af[4];
#pragma unroll
            for (int mf = 0; mf < 4; ++mf) {
                int row = wm * 64 + mf * 16 + lm;
                af[mf] = *(const bf16x8*)(As + row * 128 + ((ks * 64 + lk * 16) ^ ((row & 7) << 4)));
            }
#pragma unroll
            for (int nf = 0; nf < 4; ++nf) {
                int brow = wn * 64 + nf * 16 + lm;
                bf16x8 bf = *(const bf16x8*)(Bs + brow * 128 + ((ks * 64 + lk * 16) ^ ((brow & 7) << 4)));
#pragma unroll
                for (int mf = 0; mf < 4; ++mf)
                    acc[mf][nf] = __builtin_amdgcn_mfma_f32_16x16x32_bf16(af[mf], bf, acc[mf][nf], 0, 0, 0);
            }
        }
        __syncthreads();
    }

    unsigned short* dslice = dbuf + (size_t)slice * S_ * 2 * H_;
#pragma unroll
    for (int mf = 0; mf < 4; ++mf)
#pragma unroll
        for (int nf = 0; nf < 4; ++nf) {
            int colh = h0 + wn * 64 + nf * 16 + lm;
#pragma unroll
            for (int j = 0; j < 4; ++j) {
                int rloc = wm * 64 + mf * 16 + lk * 4 + j;
                if (p0 + rloc < c)
                    dslice[(size_t)rowslotS[rloc] * H_ + colh] = f2bf(acc[mf][nf][j]);
            }
        }
}

// ---------------- MoE up (reg-staged, WB=false fallback)
template<bool WB>
__global__ __launch_bounds__(256) void moe_up_mfma(const float* __restrict__ x2,
                                                   const void* __restrict__ w1,
                                                   const void* __restrict__ w3,
                                                   const int* __restrict__ cnt,
                                                   const int* __restrict__ elist,
                                                   const int* __restrict__ eslot,
                                                   unsigned short* __restrict__ hbuf)
{
    int e = blockIdx.z;
    int c = cnt[e];
    int p0 = blockIdx.y * 128;
    if (p0 >= c) return;
    int i0 = blockIdx.x * 64;
    int tid = threadIdx.x;

    __shared__ char As[16384], B1s[8192], B3s[8192];
    __shared__ int rowtokS[128], rowslotS[128];
    if (tid < 128) {
        int p = min(p0 + tid, c - 1);
        rowtokS[tid]  = elist[e * S_ + p];
        rowslotS[tid] = eslot[e * S_ + p];
    }
    __syncthreads();

    int lane = tid & 63, w = tid >> 6, wm = w >> 1, wn = w & 1;
    int lm = lane & 15, lk = lane >> 4;
    size_t wbase = (size_t)e * I_ * H_;

    int4 rA[4], rB1[2], rB3[2];
    auto loadAll = [&](int kb) {
#pragma unroll
        for (int it = 0; it < 4; ++it) {
            int g = tid + it * 256, row = g >> 3, kg = g & 7;
            const float* s = x2 + (size_t)rowtokS[row] * H_ + kb + kg * 8;
            float4 f0 = *(const float4*)s, f1 = *(const float4*)(s + 4);
            rA[it] = make_int4(pkbf(f0.x, f0.y), pkbf(f0.z, f0.w),
                               pkbf(f1.x, f1.y), pkbf(f1.z, f1.w));
        }
#pragma unroll
        for (int it = 0; it < 2; ++it) {
            int g = tid + it * 256, row = g >> 3, kg = g & 7;
            size_t off = wbase + (size_t)(i0 + row) * H_ + kb + kg * 8;
            rB1[it] = loadW16<WB>(w1, off);
            rB3[it] = loadW16<WB>(w3, off);
        }
    };
    auto writeAll = [&]() {
#pragma unroll
        for (int it = 0; it < 4; ++it) {
            int g = tid + it * 256, row = g >> 3, kg = g & 7;
            int byte = row * 128 + ((kg * 16) ^ ((row & 7) << 4));
            *(int4*)(As + byte) = rA[it];
        }
#pragma unroll
        for (int it = 0; it < 2; ++it) {
            int g = tid + it * 256, row = g >> 3, kg = g & 7;
            int byte = row * 128 + ((kg * 16) ^ ((row & 7) << 4));
            *(int4*)(B1s + byte) = rB1[it];
            *(int4*)(B3s + byte) = rB3[it];
        }
    };

    f32x4 z = {0.f, 0.f, 0.f, 0.f};
    f32x4 acc1[4][2], acc3[4][2];
#pragma unroll
    for (int mf = 0; mf < 4; ++mf)
#pragma unroll
        for (int nf = 0; nf < 2; ++nf) { acc1[mf][nf] = z; acc3[mf][nf] = z; }

    loadAll(0);
    for (int kt = 0; kt < H_ / 64; ++kt) {
        __syncthreads();
        writeAll();
        __syncthreads();
        if (kt + 1 < H_ / 64) loadAll((kt + 1) * 64);
#pragma unroll
        for (int ks = 0; ks < 2; ++ks) {
            bf16x8 af[4];
#pragma unroll
            for (int mf = 0; mf < 4; ++mf) {
                int row = wm * 64 + mf * 16 + lm;
                af[mf] = *(const bf16x8*)(As + row * 128 + ((ks * 64 + lk * 16) ^ ((row & 7) << 4)));
            }
#pragma unroll
            for (int nf = 0; nf < 2; ++nf) {
                int brow = wn * 32 + nf * 16 + lm;
                int bby = brow * 128 + ((ks * 64 + lk * 16) ^ ((brow & 7) << 4));
                bf16x8 b1 = *(const bf16x8*)(B1s + bby);
                bf16x8 b3 = *(const bf16x8*)(B3s + bby);
#pragma unroll
                for (int mf = 0; mf < 4; ++mf) {
                    acc1[mf][nf] = __builtin_amdgcn_mfma_f32_16x16x32_bf16(af[mf], b1, acc1[mf][nf], 0, 0, 0);
                    acc3[mf][nf] = __builtin_amdgcn_mfma_f32_16x16x32_bf16(af[mf], b3, acc3[mf][nf], 0, 0, 0);
                }
            }
        }
    }

#pragma unroll
    for (int mf = 0; mf < 4; ++mf)
#pragma unroll
        for (int nf = 0; nf < 2; ++nf) {
            int coli = i0 + wn * 32 + nf * 16 + lm;
#pragma unroll
            for (int j = 0; j < 4; ++j) {
                int rloc = wm * 64 + mf * 16 + lk * 4 + j;
                if (p0 + rloc < c) {
                    float h1 = acc1[mf][nf][j];
                    float val = h1 / (1.f + __expf(-h1)) * acc3[mf][nf][j];
                    hbuf[(size_t)rowslotS[rloc] * I_ + coli] = f2bf(val);
                }
            }
        }
}

// ---------------- MoE down (reg-staged, WB=false fallback)
template<bool WB>
__global__ __launch_bounds__(256) void moe_dn_mfma(const unsigned short* __restrict__ hbuf,
                                                   const void* __restrict__ w2,
                                                   const int* __restrict__ cnt,
                                                   const int* __restrict__ eslot,
                                                   unsigned short* __restrict__ dbuf)
{
    int e = blockIdx.z >> 2;
    int slice = blockIdx.z & 3;
    int c = cnt[e];
    int p0 = blockIdx.y * 128;
    if (p0 >= c) return;
    int h0 = blockIdx.x * 128;
    int tid = threadIdx.x;
    const int kb0 = slice * (I_ / KSLC);

    __shared__ char As[16384], Bs[16384];
    __shared__ int rowslotS[128];
    if (tid < 128) rowslotS[tid] = eslot[e * S_ + min(p0 + tid, c - 1)];
    __syncthreads();

    int lane = tid & 63, w = tid >> 6, wm = w >> 1, wn = w & 1;
    int lm = lane & 15, lk = lane >> 4;
    size_t wbase = (size_t)e * H_ * I_;

    int4 rA[4], rB[4];
    auto loadAll = [&](int kb) {
#pragma unroll
        for (int it = 0; it < 4; ++it) {
            int g = tid + it * 256, row = g >> 3, kg = g & 7;
            rA[it] = *(const int4*)(hbuf + (size_t)rowslotS[row] * I_ + kb + kg * 8);
            rB[it] = loadW16<WB>(w2, wbase + (size_t)(h0 + row) * I_ + kb + kg * 8);
        }
    };
    auto writeAll = [&]() {
#pragma unroll
        for (int it = 0; it < 4; ++it) {
            int g = tid + it * 256, row = g >> 3, kg = g & 7;
            int byte = row * 128 + ((kg * 16) ^ ((row & 7) << 4));
            *(int4*)(As + byte) = rA[it];
            *(int4*)(Bs + byte) = rB[it];
        }
    };

    f32x4 z = {0.f, 0.f, 0.f, 0.f};
    f32x4 acc[4][4];
#pragma unroll
    for (int mf = 0; mf < 4; ++mf)
#pragma unroll
        for (int nf = 0; nf < 4; ++nf) acc[mf][nf] = z;

    loadAll(kb0);
    const int NKT = (I_ / KSLC) / 64;
    for (int kt = 0; kt < NKT; ++kt) {
        __syncthreads();
        writeAll();
        __syncthreads();
        if (kt + 1 < NKT) loadAll(kb0 + (kt + 1) * 64);
#pragma unroll
        for (int ks = 0; ks < 2; ++ks) {
            bf16x8 af[4];
#pragma unroll
            for (int mf = 0; mf < 4; ++mf) {
                int row = wm * 64 + mf * 16 + lm;
                af[mf] = *(const bf16x8*)(As + row * 128 + ((ks * 64 + lk * 16) ^ ((row & 7) << 4)));
            }
#pragma unroll
            for (int nf = 0; nf < 4; ++nf) {
                int brow = wn * 64 + nf * 16 + lm;
                bf16x8 bf = *(const bf16x8*)(Bs + brow * 128 + ((ks * 64 + lk * 16) ^ ((brow & 7) << 4)));
#pragma unroll
                for (int mf = 0; mf < 4; ++mf)
                    acc[mf][nf] = __builtin_amdgcn_mfma_f32_16x16x32_bf16(af[mf], bf, acc[mf][nf], 0, 0, 0);
            }
        }
    }

    unsigned short* dslice = dbuf + (size_t)slice * S_ * 2 * H_;
#pragma unroll
    for (int mf = 0; mf < 4; ++mf)
#pragma unroll
        for (int nf = 0; nf < 4; ++nf) {
            int colh = h0 + wn * 64 + nf * 16 + lm;
#pragma unroll
            for (int j = 0; j < 4; ++j) {
                int rloc = wm * 64 + mf * 16 + lk * 4 + j;
                if (p0 + rloc < c)
                    dslice[(size_t)rowslotS[rloc] * H_ + colh] = f2bf(acc[mf][nf][j]);
            }
        }
}

// ---------------- Final combine
__global__ __launch_bounds__(256) void combine_k(const float* __restrict__ hid2,
                                                 const unsigned short* __restrict__ dbuf,
                                                 const float* __restrict__ wslot,
                                                 float* __restrict__ out)
{
    int idx = blockIdx.x * 256 + threadIdx.x;
    if (idx >= S_ * H_) return;
    int n = idx >> 10;
    int hcol = idx & (H_ - 1);
    float s0 = 0.f, s1 = 0.f;
#pragma unroll
    for (int sl = 0; sl < KSLC; ++sl) {
        const unsigned short* base = dbuf + (size_t)sl * S_ * 2 * H_;
        s0 += bf2f(base[(size_t)(2 * n)     * H_ + hcol]);
        s1 += bf2f(base[(size_t)(2 * n + 1) * H_ + hcol]);
    }
    out[idx] = hid2[idx] + wslot[2 * n] * s0 + wslot[2 * n + 1] * s1;
}

extern "C" void kernel_launch(void* const* d_in, const int* in_sizes, int n_in,
                              void* d_out, int out_size, void* d_ws, size_t ws_size,
                              hipStream_t stream)
{
    const float* hidden = (const float*)d_in[0];
    const float* ln1    = (const float*)d_in[1];
    const float* ln2    = (const float*)d_in[2];
    const float* wq     = (const float*)d_in[3];
    const float* wk     = (const float*)d_in[4];
    const float* wv     = (const float*)d_in[5];
    const float* wo     = (const float*)d_in[6];
    const float* gw     = (const float*)d_in[7];
    const float* w1     = (const float*)d_in[8];
    const float* w2     = (const float*)d_in[9];
    const float* w3     = (const float*)d_in[10];
    float* out = (float*)d_out;

    char* p = (char*)d_ws;
    auto alignp = [&]() { p = (char*)(((uintptr_t)p + 255) & ~(uintptr_t)255); };
    auto alloc_f = [&](size_t n) { alignp(); float* r = (float*)p; p += n * 4; return r; };
    auto alloc_h = [&](size_t n) { alignp(); unsigned short* r = (unsigned short*)p; p += n * 2; return r; };
    auto alloc_i = [&](size_t n) { alignp(); int* r = (int*)p; p += n * 4; return r; };

    float* xb   = alloc_f((size_t)S_ * H_);
    unsigned short* xbb = alloc_h((size_t)S_ * H_);
    float* q    = alloc_f((size_t)S_ * NH_ * HD_);
    float* kb   = alloc_f((size_t)S_ * KVH_ * HD_);
    float* vb   = alloc_f((size_t)S_ * KVH_ * HD_);
    unsigned short* qkvb = alloc_h((size_t)S_ * 2048);
    float* hid2 = alloc_f((size_t)S_ * H_);
    float* x2   = alloc_f((size_t)S_ * H_);
    unsigned short* x2b  = alloc_h((size_t)S_ * H_);
    unsigned short* ctxb = alloc_h((size_t)S_ * H_);
    unsigned short* hbuf = alloc_h((size_t)S_ * 2 * I_);
    unsigned short* dbuf = alloc_h((size_t)KSLC * S_ * 2 * H_);
    float* wslot= alloc_f((size_t)S_ * 2);
    unsigned short* qbf = alloc_h((size_t)S_ * NH_ * HD_);
    unsigned short* kbf = alloc_h((size_t)S_ * KVH_ * HD_);
    unsigned short* vtb = alloc_h((size_t)KVH_ * HD_ * S_);
    int* cnt   = alloc_i(E_);
    int* elist = alloc_i((size_t)E_ * S_);
    int* eslot = alloc_i((size_t)E_ * S_);
    float* ctx = xb;  // fallback alias

    size_t used = (size_t)(p - (char*)d_ws);
    const size_t nW = (size_t)E_ * I_ * H_;
    size_t wbf_bytes = (3 * nW + (size_t)2048 * H_ + (size_t)H_ * NH_ * HD_) * 2 + 8192;
    bool WB = ws_size > used && (ws_size - used) >= wbf_bytes;

    unsigned short *w1b = nullptr, *w3b = nullptr, *w2b = nullptr;
    unsigned short *wqkvb = nullptr, *wob = nullptr;
    if (WB) {
        w1b = alloc_h(nW); w3b = alloc_h(nW); w2b = alloc_h(nW);
        wqkvb = alloc_h((size_t)2048 * H_);
        wob = alloc_h((size_t)H_ * NH_ * HD_);
    }

    hipMemsetAsync(cnt, 0, E_ * sizeof(int), stream);

    if (WB) {
        conv3<<<dim3(1024, 3), 256, 0, stream>>>(w1, w3, w2, w1b, w3b, w2b, (long)(nW / 16));
        conv_qkvo<<<1536, 256, 0, stream>>>(wq, wk, wv, wo, wqkvb, wob);

        rmsnorm_k<<<S_, 256, 0, stream>>>(hidden, ln1, nullptr, xbb);
        dense_g<false><<<dim3(32, 16), 256, 0, stream>>>(xbb, wqkvb, nullptr, qkvb, H_, 2048);
        {
            int tot = S_ * (NH_ + KVH_) * 32;
            rope_conv_b<<<SDIV(tot, 256), 256, 0, stream>>>(qkvb, qbf, kbf);
        }
        v_trans_b<<<dim3(S_ / 64, KVH_), 256, 0, stream>>>(qkvb, vtb);
        attn_mfma<<<dim3(16, NH_, 2), 256, 0, stream>>>(qbf, kbf, vtb, nullptr, ctxb);
        dense_g<true><<<dim3(16, 16), 256, 0, stream>>>(ctxb, wob, hidden, hid2, H_, H_);

        rms2router<<<S_, 256, 0, stream>>>(hid2, ln2, gw, x2b, cnt, elist, eslot, wslot);

        moe_up_g<<<dim3(I_ / 64, S_ / 128, E_), 256, 0, stream>>>(x2b, w1b, w3b, cnt, elist, eslot, hbuf);
        moe_dn_g<<<dim3(H_ / 128, S_ / 128, E_ * KSLC), 256, 0, stream>>>(hbuf, w2b, cnt, eslot, dbuf);
    } else {
        rmsnorm_k<<<S_, 256, 0, stream>>>(hidden, ln1, xb, nullptr);
        dense_mfma<false><<<dim3(8, 16), 256, 0, stream>>>(xb, wq, nullptr, q,  S_, NH_ * HD_, H_);
        dense_mfma<false><<<dim3(4, 16), 256, 0, stream>>>(xb, wk, nullptr, kb, S_, KVH_ * HD_, H_);
        dense_mfma<false><<<dim3(4, 16), 256, 0, stream>>>(xb, wv, nullptr, vb, S_, KVH_ * HD_, H_);
        {
            int tot = S_ * (NH_ + KVH_) * 32;
            rope_conv<<<SDIV(tot, 256), 256, 0, stream>>>(q, kb, qbf, kbf);
        }
        v_trans<<<dim3(S_ / 64, KVH_), 256, 0, stream>>>(vb, vtb);
        attn_mfma<<<dim3(16, NH_, 2), 256, 0, stream>>>(qbf, kbf, vtb, ctx, ctxb);
        dense_mfma<false><<<dim3(8, 16), 256, 0, stream>>>(ctx, wo, hidden, hid2, S_, H_, NH_ * HD_);

        rmsnorm_k<<<S_, 256, 0, stream>>>(hid2, ln2, x2, nullptr);
        router_k<<<S_, 64, 0, stream>>>(x2, gw, cnt, elist, eslot, wslot);

        moe_up_mfma<false><<<dim3(I_ / 64, S_ / 128, E_), 256, 0, stream>>>(x2, w1, w3, cnt, elist, eslot, hbuf);
        moe_dn_mfma<false><<<dim3(H_ / 128, S_ / 128, E_ * KSLC), 256, 0, stream>>>(hbuf, w2, cnt, eslot, dbuf);
    }
    combine_k<<<SDIV(S_ * H_, 256), 256, 0, stream>>>(hid2, dbuf, wslot, out);
}

// Round 18
// 436.135 us; speedup vs baseline: 1.0753x; 1.0660x over previous
//
#include <hip/hip_runtime.h>
#include <hip/hip_bf16.h>
#include <math.h>

constexpr int S_ = 2048, H_ = 1024, NH_ = 16, KVH_ = 8, HD_ = 64;
constexpr int E_ = 8, I_ = 3584;
constexpr int KSLC = 4;
constexpr float EPS_ = 1e-6f;
constexpr float THETA_ = 1000000.0f;

#define SDIV(a,b) (((a)+(b)-1)/(b))

typedef __attribute__((ext_vector_type(8))) short bf16x8;
typedef __attribute__((ext_vector_type(4))) float f32x4;

__device__ inline unsigned pkbf(float a, float b) {
    unsigned r;
    asm("v_cvt_pk_bf16_f32 %0, %1, %2" : "=v"(r) : "v"(a), "v"(b));
    return r;
}
__device__ inline unsigned short f2bf(float f) {
    unsigned u = __float_as_uint(f);
    u += 0x7FFF + ((u >> 16) & 1);
    return (unsigned short)(u >> 16);
}
__device__ inline float bf2f(unsigned short v) {
    return __uint_as_float((unsigned)v << 16);
}

__device__ inline void gload16u(const void* gsrc, char* ldsArr, int uoff) {
    int off = __builtin_amdgcn_readfirstlane(uoff);
    __builtin_amdgcn_global_load_lds(
        (__attribute__((address_space(1))) void*)(gsrc),
        (__attribute__((address_space(3))) void*)(ldsArr + off), 16, 0, 0);
}
__device__ inline void vmdrain() {
    asm volatile("s_waitcnt vmcnt(0)" ::: "memory");
}

template<bool WB>
__device__ inline int4 loadW16(const void* W, size_t elemOff) {
    if constexpr (WB) {
        return *(const int4*)((const unsigned short*)W + elemOff);
    } else {
        const float* s = (const float*)W + elemOff;
        float4 f0 = *(const float4*)s, f1 = *(const float4*)(s + 4);
        return make_int4(pkbf(f0.x, f0.y), pkbf(f0.z, f0.w),
                         pkbf(f1.x, f1.y), pkbf(f1.z, f1.w));
    }
}

// ---------------- merged conv for the 3 big MoE weights (R14 exact: grid.y picks tensor)
__global__ __launch_bounds__(256) void conv3(const float* __restrict__ a,
                                             const float* __restrict__ b,
                                             const float* __restrict__ c,
                                             unsigned short* __restrict__ oa,
                                             unsigned short* __restrict__ ob,
                                             unsigned short* __restrict__ oc,
                                             long n8)
{
    int t = blockIdx.y;
    const float* in = (t == 0) ? a : (t == 1) ? b : c;
    unsigned short* out = (t == 0) ? oa : (t == 1) ? ob : oc;
    long i = (long)blockIdx.x * 256 + threadIdx.x;
    long stride = (long)gridDim.x * 256;
    for (; i < n8; i += stride) {
        const float* s = in + i * 8;
        float4 f0 = *(const float4*)s, f1 = *(const float4*)(s + 4);
        *(int4*)(out + i * 8) = make_int4(pkbf(f0.x, f0.y), pkbf(f0.z, f0.w),
                                          pkbf(f1.x, f1.y), pkbf(f1.z, f1.w));
    }
}

// ---------------- merged conv for wq|wk|wv -> wqkvb and wo -> wob
__global__ __launch_bounds__(256) void conv_qkvo(const float* __restrict__ wq,
                                                 const float* __restrict__ wk,
                                                 const float* __restrict__ wv,
                                                 const float* __restrict__ wo,
                                                 unsigned short* __restrict__ wqkvb,
                                                 unsigned short* __restrict__ wob)
{
    const long NQ = (long)NH_ * HD_ * H_ / 8;      // 131072
    const long NK = (long)KVH_ * HD_ * H_ / 8;     // 65536
    long u = (long)blockIdx.x * 256 + threadIdx.x; // grid sized exactly
    const float* in; unsigned short* out;
    if (u < NQ)                { in = wq + u * 8;               out = wqkvb + u * 8; }
    else if (u < NQ + NK)      { long v = u - NQ;      in = wk + v * 8; out = wqkvb + (NQ + v) * 8; }
    else if (u < NQ + 2 * NK)  { long v = u - NQ - NK; in = wv + v * 8; out = wqkvb + (NQ + NK + v) * 8; }
    else                       { long v = u - NQ - 2 * NK; in = wo + v * 8; out = wob + v * 8; }
    float4 f0 = *(const float4*)in, f1 = *(const float4*)(in + 4);
    *(int4*)out = make_int4(pkbf(f0.x, f0.y), pkbf(f0.z, f0.w),
                            pkbf(f1.x, f1.y), pkbf(f1.z, f1.w));
}

// ---------------- RMSNorm (fp32 out and bf16 out both optional)
__global__ __launch_bounds__(256) void rmsnorm_k(const float* __restrict__ x,
                                                 const float* __restrict__ w,
                                                 float* __restrict__ out,
                                                 unsigned short* __restrict__ outb)
{
    int row = blockIdx.x;
    int tid = threadIdx.x;
    const float* xr = x + (size_t)row * H_;
    float4 v = *(const float4*)&xr[tid * 4];
    float ss = v.x*v.x + v.y*v.y + v.z*v.z + v.w*v.w;
#pragma unroll
    for (int off = 32; off > 0; off >>= 1) ss += __shfl_xor(ss, off);
    __shared__ float red[4];
    if ((tid & 63) == 0) red[tid >> 6] = ss;
    __syncthreads();
    float tot = red[0] + red[1] + red[2] + red[3];
    float r = rsqrtf(tot / (float)H_ + EPS_);
    float4 wv = *(const float4*)&w[tid * 4];
    float4 o;
    o.x = v.x * r * wv.x; o.y = v.y * r * wv.y;
    o.z = v.z * r * wv.z; o.w = v.w * r * wv.w;
    if (out) *(float4*)&out[(size_t)row * H_ + tid * 4] = o;
    if (outb) {
        uint2 pk = make_uint2(pkbf(o.x, o.y), pkbf(o.z, o.w));
        *(uint2*)&outb[(size_t)row * H_ + tid * 4] = pk;
    }
}

// ---------------- Fused RMSNorm2 + router (WB path)
__global__ __launch_bounds__(256) void rms2router(const float* __restrict__ x,
                                                  const float* __restrict__ w,
                                                  const float* __restrict__ gw,
                                                  unsigned short* __restrict__ outb,
                                                  int* __restrict__ cnt,
                                                  int* __restrict__ elist,
                                                  int* __restrict__ eslot,
                                                  float* __restrict__ wslot)
{
    int row = blockIdx.x;
    int tid = threadIdx.x;
    const float* xr = x + (size_t)row * H_;
    float4 v = *(const float4*)&xr[tid * 4];
    float ss = v.x*v.x + v.y*v.y + v.z*v.z + v.w*v.w;
#pragma unroll
    for (int off = 32; off > 0; off >>= 1) ss += __shfl_xor(ss, off);
    __shared__ float red[4];
    __shared__ float redE[4][8];
    if ((tid & 63) == 0) red[tid >> 6] = ss;
    __syncthreads();
    float tot = red[0] + red[1] + red[2] + red[3];
    float r = rsqrtf(tot / (float)H_ + EPS_);
    float4 wv = *(const float4*)&w[tid * 4];
    float o0 = v.x * r * wv.x, o1 = v.y * r * wv.y;
    float o2 = v.z * r * wv.z, o3 = v.w * r * wv.w;
    uint2 pk = make_uint2(pkbf(o0, o1), pkbf(o2, o3));
    *(uint2*)&outb[(size_t)row * H_ + tid * 4] = pk;

    int col = tid * 4;
    float part[E_];
#pragma unroll
    for (int e = 0; e < E_; ++e) {
        const float* g = gw + (size_t)e * H_ + col;
        part[e] = o0 * g[0] + o1 * g[1] + o2 * g[2] + o3 * g[3];
    }
#pragma unroll
    for (int e = 0; e < E_; ++e)
#pragma unroll
        for (int off = 32; off > 0; off >>= 1) part[e] += __shfl_xor(part[e], off);
    if ((tid & 63) == 0)
#pragma unroll
        for (int e = 0; e < E_; ++e) redE[tid >> 6][e] = part[e];
    __syncthreads();
    if (tid == 0) {
        float lg[E_];
#pragma unroll
        for (int e = 0; e < E_; ++e)
            lg[e] = redE[0][e] + redE[1][e] + redE[2][e] + redE[3][e];
        float mx = lg[0];
#pragma unroll
        for (int e = 1; e < E_; ++e) mx = fmaxf(mx, lg[e]);
        float rw[E_]; float ssum = 0.f;
#pragma unroll
        for (int e = 0; e < E_; ++e) { rw[e] = expf(lg[e] - mx); ssum += rw[e]; }
#pragma unroll
        for (int e = 0; e < E_; ++e) rw[e] /= ssum;
        float best = -1.f; int ba = 0, bb = 1;
        for (int a = 0; a < E_; ++a)
            for (int b = a + 1; b < E_; ++b) {
                float scv = rw[a] + rw[b];
                if (scv > best) { best = scv; ba = a; bb = b; }
            }
        float wa = rw[ba], wb = rw[bb], wsum = wa + wb;
        wa /= wsum; wb /= wsum;
        int n = row;
        int p = atomicAdd(&cnt[ba], 1);
        elist[ba * S_ + p] = n; eslot[ba * S_ + p] = 2 * n;
        p = atomicAdd(&cnt[bb], 1);
        elist[bb * S_ + p] = n; eslot[bb * S_ + p] = 2 * n + 1;
        wslot[2 * n] = wa; wslot[2 * n + 1] = wb;
    }
}

// ---------------- Dense g-style GEMM (WB path): 128(M) x 64(N), BK=64. Hoisted addrs.
template<bool OUTF32>
__global__ __launch_bounds__(256) void dense_g(const unsigned short* __restrict__ A,
                                               const unsigned short* __restrict__ B,
                                               const float* __restrict__ Res,
                                               void* __restrict__ C,
                                               int K, int ldC)
{
    int m0 = blockIdx.y * 128, n0 = blockIdx.x * 64;
    int tid = threadIdx.x;
    __shared__ char As[16384], Bs[8192];
    int lane = tid & 63, w = tid >> 6, wm = w >> 1, wn = w & 1;
    int lm = lane & 15, lk = lane >> 4;
    int wb16 = (tid & ~63) * 16;

    const unsigned short* aSrc[4];
    const unsigned short* bSrc[2];
#pragma unroll
    for (int it = 0; it < 4; ++it) {
        int g = tid + it * 256, row = g >> 3, kg = g & 7;
        int kgs = kg ^ (row & 7);
        aSrc[it] = A + (size_t)(m0 + row) * K + kgs * 8;
    }
#pragma unroll
    for (int it = 0; it < 2; ++it) {
        int g = tid + it * 256, row = g >> 3, kg = g & 7;
        int kgs = kg ^ (row & 7);
        bSrc[it] = B + (size_t)(n0 + row) * K + kgs * 8;
    }

    f32x4 z = {0.f, 0.f, 0.f, 0.f};
    f32x4 acc[4][2];
#pragma unroll
    for (int mf = 0; mf < 4; ++mf)
#pragma unroll
        for (int nf = 0; nf < 2; ++nf) acc[mf][nf] = z;

    for (int kt = 0; kt < K / 64; ++kt) {
        int kb = kt * 64;
#pragma unroll
        for (int it = 0; it < 4; ++it)
            gload16u(aSrc[it] + kb, As, wb16 + it * 4096);
#pragma unroll
        for (int it = 0; it < 2; ++it)
            gload16u(bSrc[it] + kb, Bs, wb16 + it * 4096);
        vmdrain();
        __syncthreads();
#pragma unroll
        for (int ks = 0; ks < 2; ++ks) {
            bf16x8 af[4];
#pragma unroll
            for (int mf = 0; mf < 4; ++mf) {
                int row = wm * 64 + mf * 16 + lm;
                af[mf] = *(const bf16x8*)(As + row * 128 + ((ks * 64 + lk * 16) ^ ((row & 7) << 4)));
            }
#pragma unroll
            for (int nf = 0; nf < 2; ++nf) {
                int brow = wn * 32 + nf * 16 + lm;
                bf16x8 bf = *(const bf16x8*)(Bs + brow * 128 + ((ks * 64 + lk * 16) ^ ((brow & 7) << 4)));
#pragma unroll
                for (int mf = 0; mf < 4; ++mf)
                    acc[mf][nf] = __builtin_amdgcn_mfma_f32_16x16x32_bf16(af[mf], bf, acc[mf][nf], 0, 0, 0);
            }
        }
        __syncthreads();
    }

#pragma unroll
    for (int mf = 0; mf < 4; ++mf)
#pragma unroll
        for (int nf = 0; nf < 2; ++nf) {
            int col = n0 + wn * 32 + nf * 16 + lm;
#pragma unroll
            for (int j = 0; j < 4; ++j) {
                int row = m0 + wm * 64 + mf * 16 + lk * 4 + j;
                float v = acc[mf][nf][j];
                if constexpr (OUTF32) {
                    float r = Res ? Res[(size_t)row * ldC + col] : 0.0f;
                    ((float*)C)[(size_t)row * ldC + col] = v + r;
                } else {
                    ((unsigned short*)C)[(size_t)row * ldC + col] = f2bf(v);
                }
            }
        }
}

// ---------------- Dense bf16-MFMA GEMM (reg-staged; WB=false fallback)
template<bool WB>
__global__ __launch_bounds__(256) void dense_mfma(const float* __restrict__ A,
                                                  const void* __restrict__ Bw,
                                                  const float* __restrict__ Res,
                                                  float* __restrict__ C,
                                                  int M, int N, int K)
{
    __shared__ char As[16384], Bs[16384];
    int tid = threadIdx.x;
    int m0 = blockIdx.y * 128, n0 = blockIdx.x * 128;
    int lane = tid & 63, w = tid >> 6, wm = w >> 1, wn = w & 1;
    int lm = lane & 15, lk = lane >> 4;

    int4 rA[4], rB[4];
    auto loadAll = [&](int kb) {
#pragma unroll
        for (int it = 0; it < 4; ++it) {
            int g = tid + it * 256, row = g >> 3, kg = g & 7;
            const float* s = A + (size_t)(m0 + row) * K + kb + kg * 8;
            float4 f0 = *(const float4*)s, f1 = *(const float4*)(s + 4);
            rA[it] = make_int4(pkbf(f0.x, f0.y), pkbf(f0.z, f0.w),
                               pkbf(f1.x, f1.y), pkbf(f1.z, f1.w));
            rB[it] = loadW16<WB>(Bw, (size_t)(n0 + row) * K + kb + kg * 8);
        }
    };
    auto writeAll = [&]() {
#pragma unroll
        for (int it = 0; it < 4; ++it) {
            int g = tid + it * 256, row = g >> 3, kg = g & 7;
            int byte = row * 128 + ((kg * 16) ^ ((row & 7) << 4));
            *(int4*)(As + byte) = rA[it];
            *(int4*)(Bs + byte) = rB[it];
        }
    };

    f32x4 z = {0.f, 0.f, 0.f, 0.f};
    f32x4 acc[4][4];
#pragma unroll
    for (int mf = 0; mf < 4; ++mf)
#pragma unroll
        for (int nf = 0; nf < 4; ++nf) acc[mf][nf] = z;

    loadAll(0);
    for (int kt = 0; kt < K / 64; ++kt) {
        __syncthreads();
        writeAll();
        __syncthreads();
        if (kt + 1 < K / 64) loadAll((kt + 1) * 64);
#pragma unroll
        for (int ks = 0; ks < 2; ++ks) {
            bf16x8 af[4];
#pragma unroll
            for (int mf = 0; mf < 4; ++mf) {
                int row = wm * 64 + mf * 16 + lm;
                af[mf] = *(const bf16x8*)(As + row * 128 + ((ks * 64 + lk * 16) ^ ((row & 7) << 4)));
            }
#pragma unroll
            for (int nf = 0; nf < 4; ++nf) {
                int brow = wn * 64 + nf * 16 + lm;
                bf16x8 bf = *(const bf16x8*)(Bs + brow * 128 + ((ks * 64 + lk * 16) ^ ((brow & 7) << 4)));
#pragma unroll
                for (int mf = 0; mf < 4; ++mf)
                    acc[mf][nf] = __builtin_amdgcn_mfma_f32_16x16x32_bf16(af[mf], bf, acc[mf][nf], 0, 0, 0);
            }
        }
    }

#pragma unroll
    for (int mf = 0; mf < 4; ++mf)
#pragma unroll
        for (int nf = 0; nf < 4; ++nf) {
            int col = n0 + wn * 64 + nf * 16 + lm;
#pragma unroll
            for (int j = 0; j < 4; ++j) {
                int row = m0 + wm * 64 + mf * 16 + lk * 4 + j;
                float r = Res ? Res[(size_t)row * N + col] : 0.0f;
                C[(size_t)row * N + col] = acc[mf][nf][j] + r;
            }
        }
}

// ---------------- RoPE + bf16 (WB path): reads fused bf16 qkvb [S][2048]
__global__ __launch_bounds__(256) void rope_conv_b(const unsigned short* __restrict__ qkvb,
                                                   unsigned short* __restrict__ qbf,
                                                   unsigned short* __restrict__ kbf)
{
    int idx = blockIdx.x * 256 + threadIdx.x;
    const int totq = S_ * NH_ * 32;
    const int tot = totq + S_ * KVH_ * 32;
    if (idx >= tot) return;
    const unsigned short* src; unsigned short* dst; int s, di; float sc;
    if (idx < totq) {
        s = idx / (NH_ * 32); int r = idx % (NH_ * 32); int h = r >> 5;
        src = qkvb + (size_t)s * 2048 + h * 64;
        dst = qbf + ((size_t)s * NH_ + h) * HD_;
        di = r & 31; sc = 0.125f;
    } else {
        int j2 = idx - totq;
        s = j2 / (KVH_ * 32); int r = j2 % (KVH_ * 32); int kvh = r >> 5;
        src = qkvb + (size_t)s * 2048 + 1024 + kvh * 64;
        dst = kbf + ((size_t)s * KVH_ + kvh) * HD_;
        di = r & 31; sc = 1.0f;
    }
    float invf = powf(THETA_, -(2.0f * di) / (float)HD_);
    float ang = (float)s * invf;
    float c = cosf(ang), sn = sinf(ang);
    float x0 = bf2f(src[di]), x1 = bf2f(src[di + 32]);
    dst[di]      = f2bf((x0 * c - x1 * sn) * sc);
    dst[di + 32] = f2bf((x1 * c + x0 * sn) * sc);
}

// ---------------- V transpose (WB path): V from qkvb cols [1536..2048)
__global__ __launch_bounds__(256) void v_trans_b(const unsigned short* __restrict__ qkvb,
                                                 unsigned short* __restrict__ vtb)
{
    int t0 = blockIdx.x * 64, kvh = blockIdx.y;
    __shared__ unsigned short T[64][64];
    int tid = threadIdx.x;
    int k = tid >> 2, d0 = (tid & 3) * 16;
    const unsigned short* src = qkvb + (size_t)(t0 + k) * 2048 + 1536 + kvh * 64 + d0;
    *(int4*)&T[k][d0]     = *(const int4*)(src);
    *(int4*)&T[k][d0 + 8] = *(const int4*)(src + 8);
    __syncthreads();
    int d = tid >> 2, s0 = (tid & 3) * 16;
    unsigned short tmp[16] __attribute__((aligned(16)));
#pragma unroll
    for (int x = 0; x < 16; ++x) {
        int s = s0 + x;
        int key = 16 * (s & 3) + (s >> 2);
        tmp[x] = T[key][d];
    }
    unsigned short* dst = vtb + ((size_t)kvh * HD_ + d) * S_ + t0 + s0;
    *(int4*)(dst)     = *(int4*)(tmp);
    *(int4*)(dst + 8) = *(int4*)(tmp + 8);
}

// ---------------- RoPE + bf16 convert (fallback: fp32 q/k inputs)
__global__ __launch_bounds__(256) void rope_conv(const float* __restrict__ q,
                                                 const float* __restrict__ k,
                                                 unsigned short* __restrict__ qbf,
                                                 unsigned short* __restrict__ kbf)
{
    int idx = blockIdx.x * 256 + threadIdx.x;
    const int totq = S_ * NH_ * 32;
    const int tot = totq + S_ * KVH_ * 32;
    if (idx >= tot) return;
    const float* base; unsigned short* obase; int s, di; float sc;
    if (idx < totq) {
        s = idx / (NH_ * 32); int r = idx % (NH_ * 32);
        size_t o = ((size_t)s * NH_ + (r >> 5)) * HD_;
        base = q + o; obase = qbf + o; di = r & 31; sc = 0.125f;
    } else {
        int j2 = idx - totq;
        s = j2 / (KVH_ * 32); int r = j2 % (KVH_ * 32);
        size_t o = ((size_t)s * KVH_ + (r >> 5)) * HD_;
        base = k + o; obase = kbf + o; di = r & 31; sc = 1.0f;
    }
    float invf = powf(THETA_, -(2.0f * di) / (float)HD_);
    float ang = (float)s * invf;
    float c = cosf(ang), sn = sinf(ang);
    float x0 = base[di], x1 = base[di + 32];
    obase[di]      = f2bf((x0 * c - x1 * sn) * sc);
    obase[di + 32] = f2bf((x1 * c + x0 * sn) * sc);
}

// ---------------- V transpose (fallback: fp32 V input)
__global__ __launch_bounds__(256) void v_trans(const float* __restrict__ v,
                                               unsigned short* __restrict__ vtb)
{
    int t0 = blockIdx.x * 64, kvh = blockIdx.y;
    __shared__ unsigned short T[64][64];
    int tid = threadIdx.x;
    int k = tid >> 2, d0 = (tid & 3) * 16;
    const float* src = v + ((size_t)(t0 + k) * KVH_ + kvh) * HD_ + d0;
#pragma unroll
    for (int x = 0; x < 4; ++x) {
        float4 f = *(const float4*)(src + x * 4);
        T[k][d0 + x*4 + 0] = f2bf(f.x);
        T[k][d0 + x*4 + 1] = f2bf(f.y);
        T[k][d0 + x*4 + 2] = f2bf(f.z);
        T[k][d0 + x*4 + 3] = f2bf(f.w);
    }
    __syncthreads();
    int d = tid >> 2, s0 = (tid & 3) * 16;
    unsigned short tmp[16] __attribute__((aligned(16)));
#pragma unroll
    for (int x = 0; x < 16; ++x) {
        int s = s0 + x;
        int key = 16 * (s & 3) + (s >> 2);
        tmp[x] = T[key][d];
    }
    unsigned short* dst = vtb + ((size_t)kvh * HD_ + d) * S_ + t0 + s0;
    *(int4*)(dst)     = *(int4*)(tmp);
    *(int4*)(dst + 8) = *(int4*)(tmp + 8);
}

// ---------------- MFMA flash attention (fp32 ctx optional; defer-max softmax)
__global__ __launch_bounds__(256) void attn_mfma(const unsigned short* __restrict__ qbf,
                                                 const unsigned short* __restrict__ kbf,
                                                 const unsigned short* __restrict__ vtb,
                                                 float* __restrict__ ctx,
                                                 unsigned short* __restrict__ ctxb)
{
    __shared__ char Ps[4 * 2048];
    int pair = blockIdx.x, h = blockIdx.y, z = blockIdx.z;
    int qb = z ? (31 - pair) : pair;
    int q0 = qb * 64;
    int kvh = h >> 1;
    int tid = threadIdx.x;
    int w = tid >> 6, lane = tid & 63;
    int lm = lane & 15, lk = lane >> 4;
    char* myP = Ps + w * 2048;

    bf16x8 qf[2];
    const unsigned short* qrow = qbf + ((size_t)(q0 + w * 16 + lm) * NH_ + h) * HD_;
#pragma unroll
    for (int ks = 0; ks < 2; ++ks)
        qf[ks] = *(const bf16x8*)(qrow + ks * 32 + lk * 8);

    float m_[4], l_[4];
    f32x4 o_[4];
#pragma unroll
    for (int j = 0; j < 4; ++j) { m_[j] = -1e30f; l_[j] = 0.f; }
    f32x4 zf = {0.f, 0.f, 0.f, 0.f};
#pragma unroll
    for (int nd = 0; nd < 4; ++nd) o_[nd] = zf;

    for (int t0 = 0; t0 <= q0; t0 += 64) {
        f32x4 s[4];
#pragma unroll
        for (int nf = 0; nf < 4; ++nf) {
            const unsigned short* krow = kbf + ((size_t)(t0 + nf * 16 + lm) * KVH_ + kvh) * HD_;
            bf16x8 k0 = *(const bf16x8*)(krow + lk * 8);
            bf16x8 k1 = *(const bf16x8*)(krow + 32 + lk * 8);
            f32x4 acc = zf;
            acc = __builtin_amdgcn_mfma_f32_16x16x32_bf16(qf[0], k0, acc, 0, 0, 0);
            acc = __builtin_amdgcn_mfma_f32_16x16x32_bf16(qf[1], k1, acc, 0, 0, 0);
            s[nf] = acc;
        }
        if (t0 == q0) {
#pragma unroll
            for (int nf = 0; nf < 4; ++nf)
#pragma unroll
                for (int j = 0; j < 4; ++j) {
                    int key = nf * 16 + lm, qq = w * 16 + lk * 4 + j;
                    if (key > qq) s[nf][j] = -1e30f;
                }
        }
        float p_[4][4];
#pragma unroll
        for (int j = 0; j < 4; ++j) {
            float mx = fmaxf(fmaxf(s[0][j], s[1][j]), fmaxf(s[2][j], s[3][j]));
#pragma unroll
            for (int off = 8; off > 0; off >>= 1) mx = fmaxf(mx, __shfl_xor(mx, off));
            if (mx > m_[j] + 8.f) {
                float rs = __expf(m_[j] - mx);
                m_[j] = mx;
                l_[j] *= rs;
#pragma unroll
                for (int nd = 0; nd < 4; ++nd) o_[nd][j] *= rs;
            }
            float sum = 0.f;
#pragma unroll
            for (int nf = 0; nf < 4; ++nf) {
                float pv = __expf(s[nf][j] - m_[j]);
                p_[nf][j] = pv; sum += pv;
            }
#pragma unroll
            for (int off = 8; off > 0; off >>= 1) sum += __shfl_xor(sum, off);
            l_[j] += sum;
        }
#pragma unroll
        for (int j = 0; j < 4; ++j) {
            int r = lk * 4 + j;
            unsigned lo = pkbf(p_[0][j], p_[1][j]);
            unsigned hi = pkbf(p_[2][j], p_[3][j]);
            int byte = (lm * 8) ^ ((r & 7) << 4);
            *(uint2*)(myP + r * 128 + byte) = make_uint2(lo, hi);
        }
#pragma unroll
        for (int ks = 0; ks < 2; ++ks) {
            int byte = (ks * 64 + lk * 16) ^ ((lm & 7) << 4);
            bf16x8 pA = *(const bf16x8*)(myP + lm * 128 + byte);
#pragma unroll
            for (int nd = 0; nd < 4; ++nd) {
                const unsigned short* vrow = vtb + ((size_t)kvh * HD_ + nd * 16 + lm) * S_ + t0 + ks * 32 + lk * 8;
                bf16x8 vB = *(const bf16x8*)vrow;
                o_[nd] = __builtin_amdgcn_mfma_f32_16x16x32_bf16(pA, vB, o_[nd], 0, 0, 0);
            }
        }
    }
#pragma unroll
    for (int nd = 0; nd < 4; ++nd)
#pragma unroll
        for (int j = 0; j < 4; ++j) {
            int r = lk * 4 + j;
            float val = o_[nd][j] / l_[j];
            size_t oidx = ((size_t)(q0 + w * 16 + r) * NH_ + h) * HD_ + nd * 16 + lm;
            if (ctx) ctx[oidx] = val;
            ctxb[oidx] = f2bf(val);
        }
}

// ---------------- Router (fallback path)
__global__ __launch_bounds__(64) void router_k(const float* __restrict__ x2,
                                               const float* __restrict__ gw,
                                               int* __restrict__ cnt,
                                               int* __restrict__ elist,
                                               int* __restrict__ eslot,
                                               float* __restrict__ wslot)
{
    int n = blockIdx.x, lane = threadIdx.x;
    float part[E_];
#pragma unroll
    for (int e = 0; e < E_; ++e) part[e] = 0.f;
    const float* xr = x2 + (size_t)n * H_;
    for (int j = lane; j < H_; j += 64) {
        float xv = xr[j];
#pragma unroll
        for (int e = 0; e < E_; ++e) part[e] = fmaf(xv, gw[e * H_ + j], part[e]);
    }
#pragma unroll
    for (int e = 0; e < E_; ++e)
#pragma unroll
        for (int off = 32; off > 0; off >>= 1) part[e] += __shfl_xor(part[e], off);
    if (lane == 0) {
        float mx = part[0];
#pragma unroll
        for (int e = 1; e < E_; ++e) mx = fmaxf(mx, part[e]);
        float rw[E_]; float ssum = 0.f;
#pragma unroll
        for (int e = 0; e < E_; ++e) { rw[e] = expf(part[e] - mx); ssum += rw[e]; }
#pragma unroll
        for (int e = 0; e < E_; ++e) rw[e] /= ssum;
        float best = -1.f; int ba = 0, bb = 1;
        for (int a = 0; a < E_; ++a)
            for (int b = a + 1; b < E_; ++b) {
                float scv = rw[a] + rw[b];
                if (scv > best) { best = scv; ba = a; bb = b; }
            }
        float wa = rw[ba], wb = rw[bb], wsum = wa + wb;
        wa /= wsum; wb /= wsum;
        int p = atomicAdd(&cnt[ba], 1);
        elist[ba * S_ + p] = n; eslot[ba * S_ + p] = 2 * n;
        p = atomicAdd(&cnt[bb], 1);
        elist[bb * S_ + p] = n; eslot[bb * S_ + p] = 2 * n + 1;
        wslot[2 * n] = wa; wslot[2 * n + 1] = wb;
    }
}

// ---------------- MoE up (WB path): 128x64, BK=64, single-buffer gload, hoisted addrs.
__global__ __launch_bounds__(256) void moe_up_g(const unsigned short* __restrict__ x2b,
                                                const unsigned short* __restrict__ w1b,
                                                const unsigned short* __restrict__ w3b,
                                                const int* __restrict__ cnt,
                                                const int* __restrict__ elist,
                                                const int* __restrict__ eslot,
                                                unsigned short* __restrict__ hbuf)
{
    int e = blockIdx.z;
    int c = cnt[e];
    int p0 = blockIdx.y * 128;
    if (p0 >= c) return;
    int i0 = blockIdx.x * 64;
    int tid = threadIdx.x;

    __shared__ char As[16384], B1s[8192], B3s[8192];
    __shared__ int rowtokS[128], rowslotS[128];
    if (tid < 128) {
        int p = min(p0 + tid, c - 1);
        rowtokS[tid]  = elist[e * S_ + p];
        rowslotS[tid] = eslot[e * S_ + p];
    }
    __syncthreads();

    int lane = tid & 63, w = tid >> 6, wm = w >> 1, wn = w & 1;
    int lm = lane & 15, lk = lane >> 4;
    int wb16 = (tid & ~63) * 16;
    size_t wbase = (size_t)e * I_ * H_;

    const unsigned short* aSrc[4];
    const unsigned short* b1Src[2];
    const unsigned short* b3Src[2];
#pragma unroll
    for (int it = 0; it < 4; ++it) {
        int g = tid + it * 256, row = g >> 3, kg = g & 7;
        int kgs = kg ^ (row & 7);
        aSrc[it] = x2b + (size_t)rowtokS[row] * H_ + kgs * 8;
    }
#pragma unroll
    for (int it = 0; it < 2; ++it) {
        int g = tid + it * 256, row = g >> 3, kg = g & 7;
        int kgs = kg ^ (row & 7);
        size_t off = wbase + (size_t)(i0 + row) * H_ + kgs * 8;
        b1Src[it] = w1b + off;
        b3Src[it] = w3b + off;
    }

    f32x4 z = {0.f, 0.f, 0.f, 0.f};
    f32x4 acc1[4][2], acc3[4][2];
#pragma unroll
    for (int mf = 0; mf < 4; ++mf)
#pragma unroll
        for (int nf = 0; nf < 2; ++nf) { acc1[mf][nf] = z; acc3[mf][nf] = z; }

    for (int kt = 0; kt < H_ / 64; ++kt) {
        int kb = kt * 64;
#pragma unroll
        for (int it = 0; it < 4; ++it)
            gload16u(aSrc[it] + kb, As, wb16 + it * 4096);
#pragma unroll
        for (int it = 0; it < 2; ++it) {
            gload16u(b1Src[it] + kb, B1s, wb16 + it * 4096);
            gload16u(b3Src[it] + kb, B3s, wb16 + it * 4096);
        }
        vmdrain();
        __syncthreads();
#pragma unroll
        for (int ks = 0; ks < 2; ++ks) {
            bf16x8 af[4];
#pragma unroll
            for (int mf = 0; mf < 4; ++mf) {
                int row = wm * 64 + mf * 16 + lm;
                af[mf] = *(const bf16x8*)(As + row * 128 + ((ks * 64 + lk * 16) ^ ((row & 7) << 4)));
            }
#pragma unroll
            for (int nf = 0; nf < 2; ++nf) {
                int brow = wn * 32 + nf * 16 + lm;
                int bby = brow * 128 + ((ks * 64 + lk * 16) ^ ((brow & 7) << 4));
                bf16x8 b1 = *(const bf16x8*)(B1s + bby);
                bf16x8 b3 = *(const bf16x8*)(B3s + bby);
#pragma unroll
                for (int mf = 0; mf < 4; ++mf) {
                    acc1[mf][nf] = __builtin_amdgcn_mfma_f32_16x16x32_bf16(af[mf], b1, acc1[mf][nf], 0, 0, 0);
                    acc3[mf][nf] = __builtin_amdgcn_mfma_f32_16x16x32_bf16(af[mf], b3, acc3[mf][nf], 0, 0, 0);
                }
            }
        }
        __syncthreads();
    }

#pragma unroll
    for (int mf = 0; mf < 4; ++mf)
#pragma unroll
        for (int nf = 0; nf < 2; ++nf) {
            int coli = i0 + wn * 32 + nf * 16 + lm;
#pragma unroll
            for (int j = 0; j < 4; ++j) {
                int rloc = wm * 64 + mf * 16 + lk * 4 + j;
                if (p0 + rloc < c) {
                    float h1 = acc1[mf][nf][j];
                    float val = h1 / (1.f + __expf(-h1)) * acc3[mf][nf][j];
                    hbuf[(size_t)rowslotS[rloc] * I_ + coli] = f2bf(val);
                }
            }
        }
}

// ---------------- MoE down (WB path): 128x128, BK=64, split-K, single-buffer, hoisted.
__global__ __launch_bounds__(256) void moe_dn_g(const unsigned short* __restrict__ hbuf,
                                                const unsigned short* __restrict__ w2b,
                                                const int* __restrict__ cnt,
                                                const int* __restrict__ eslot,
                                                unsigned short* __restrict__ dbuf)
{
    int e = blockIdx.z >> 2;
    int slice = blockIdx.z & 3;
    int c = cnt[e];
    int p0 = blockIdx.y * 128;
    if (p0 >= c) return;
    int h0 = blockIdx.x * 128;
    int tid = threadIdx.x;
    const int kb0 = slice * (I_ / KSLC);

    __shared__ char As[16384], Bs[16384];
    __shared__ int rowslotS[128];
    if (tid < 128) rowslotS[tid] = eslot[e * S_ + min(p0 + tid, c - 1)];
    __syncthreads();

    int lane = tid & 63, w = tid >> 6, wm = w >> 1, wn = w & 1;
    int lm = lane & 15, lk = lane >> 4;
    int wb16 = (tid & ~63) * 16;
    size_t wbase = (size_t)e * H_ * I_;

    const unsigned short* aSrc[4];
    const unsigned short* bSrc[4];
#pragma unroll
    for (int it = 0; it < 4; ++it) {
        int g = tid + it * 256, row = g >> 3, kg = g & 7;
        int kgs = kg ^ (row & 7);
        aSrc[it] = hbuf + (size_t)rowslotS[row] * I_ + kb0 + kgs * 8;
        bSrc[it] = w2b + wbase + (size_t)(h0 + row) * I_ + kb0 + kgs * 8;
    }

    f32x4 z = {0.f, 0.f, 0.f, 0.f};
    f32x4 acc[4][4];
#pragma unroll
    for (int mf = 0; mf < 4; ++mf)
#pragma unroll
        for (int nf = 0; nf < 4; ++nf) acc[mf][nf] = z;

    const int NKT = (I_ / KSLC) / 64;
    for (int kt = 0; kt < NKT; ++kt) {
        int kb = kt * 64;
#pragma unroll
        for (int it = 0; it < 4; ++it) {
            gload16u(aSrc[it] + kb, As, wb16 + it * 4096);
            gload16u(bSrc[it] + kb, Bs, wb16 + it * 4096);
        }
        vmdrain();
        __syncthreads();
#pragma unroll
        for (int ks = 0; ks < 2; ++ks) {
            bf16x8 af[4];
#pragma unroll
            for (int mf = 0; mf < 4; ++mf) {
                int row = wm * 64 + mf * 16 + lm;
                af[mf] = *(const bf16x8*)(As + row * 128 + ((ks * 64 + lk * 16) ^ ((row & 7) << 4)));
            }
#pragma unroll
            for (int nf = 0; nf < 4; ++nf) {
                int brow = wn * 64 + nf * 16 + lm;
                bf16x8 bf = *(const bf16x8*)(Bs + brow * 128 + ((ks * 64 + lk * 16) ^ ((brow & 7) << 4)));
#pragma unroll
                for (int mf = 0; mf < 4; ++mf)
                    acc[mf][nf] = __builtin_amdgcn_mfma_f32_16x16x32_bf16(af[mf], bf, acc[mf][nf], 0, 0, 0);
            }
        }
        __syncthreads();
    }

    unsigned short* dslice = dbuf + (size_t)slice * S_ * 2 * H_;
#pragma unroll
    for (int mf = 0; mf < 4; ++mf)
#pragma unroll
        for (int nf = 0; nf < 4; ++nf) {
            int colh = h0 + wn * 64 + nf * 16 + lm;
#pragma unroll
            for (int j = 0; j < 4; ++j) {
                int rloc = wm * 64 + mf * 16 + lk * 4 + j;
                if (p0 + rloc < c)
                    dslice[(size_t)rowslotS[rloc] * H_ + colh] = f2bf(acc[mf][nf][j]);
            }
        }
}

// ---------------- MoE up (reg-staged, WB=false fallback)
template<bool WB>
__global__ __launch_bounds__(256) void moe_up_mfma(const float* __restrict__ x2,
                                                   const void* __restrict__ w1,
                                                   const void* __restrict__ w3,
                                                   const int* __restrict__ cnt,
                                                   const int* __restrict__ elist,
                                                   const int* __restrict__ eslot,
                                                   unsigned short* __restrict__ hbuf)
{
    int e = blockIdx.z;
    int c = cnt[e];
    int p0 = blockIdx.y * 128;
    if (p0 >= c) return;
    int i0 = blockIdx.x * 64;
    int tid = threadIdx.x;

    __shared__ char As[16384], B1s[8192], B3s[8192];
    __shared__ int rowtokS[128], rowslotS[128];
    if (tid < 128) {
        int p = min(p0 + tid, c - 1);
        rowtokS[tid]  = elist[e * S_ + p];
        rowslotS[tid] = eslot[e * S_ + p];
    }
    __syncthreads();

    int lane = tid & 63, w = tid >> 6, wm = w >> 1, wn = w & 1;
    int lm = lane & 15, lk = lane >> 4;
    size_t wbase = (size_t)e * I_ * H_;

    int4 rA[4], rB1[2], rB3[2];
    auto loadAll = [&](int kb) {
#pragma unroll
        for (int it = 0; it < 4; ++it) {
            int g = tid + it * 256, row = g >> 3, kg = g & 7;
            const float* s = x2 + (size_t)rowtokS[row] * H_ + kb + kg * 8;
            float4 f0 = *(const float4*)s, f1 = *(const float4*)(s + 4);
            rA[it] = make_int4(pkbf(f0.x, f0.y), pkbf(f0.z, f0.w),
                               pkbf(f1.x, f1.y), pkbf(f1.z, f1.w));
        }
#pragma unroll
        for (int it = 0; it < 2; ++it) {
            int g = tid + it * 256, row = g >> 3, kg = g & 7;
            size_t off = wbase + (size_t)(i0 + row) * H_ + kb + kg * 8;
            rB1[it] = loadW16<WB>(w1, off);
            rB3[it] = loadW16<WB>(w3, off);
        }
    };
    auto writeAll = [&]() {
#pragma unroll
        for (int it = 0; it < 4; ++it) {
            int g = tid + it * 256, row = g >> 3, kg = g & 7;
            int byte = row * 128 + ((kg * 16) ^ ((row & 7) << 4));
            *(int4*)(As + byte) = rA[it];
        }
#pragma unroll
        for (int it = 0; it < 2; ++it) {
            int g = tid + it * 256, row = g >> 3, kg = g & 7;
            int byte = row * 128 + ((kg * 16) ^ ((row & 7) << 4));
            *(int4*)(B1s + byte) = rB1[it];
            *(int4*)(B3s + byte) = rB3[it];
        }
    };

    f32x4 z = {0.f, 0.f, 0.f, 0.f};
    f32x4 acc1[4][2], acc3[4][2];
#pragma unroll
    for (int mf = 0; mf < 4; ++mf)
#pragma unroll
        for (int nf = 0; nf < 2; ++nf) { acc1[mf][nf] = z; acc3[mf][nf] = z; }

    loadAll(0);
    for (int kt = 0; kt < H_ / 64; ++kt) {
        __syncthreads();
        writeAll();
        __syncthreads();
        if (kt + 1 < H_ / 64) loadAll((kt + 1) * 64);
#pragma unroll
        for (int ks = 0; ks < 2; ++ks) {
            bf16x8 af[4];
#pragma unroll
            for (int mf = 0; mf < 4; ++mf) {
                int row = wm * 64 + mf * 16 + lm;
                af[mf] = *(const bf16x8*)(As + row * 128 + ((ks * 64 + lk * 16) ^ ((row & 7) << 4)));
            }
#pragma unroll
            for (int nf = 0; nf < 2; ++nf) {
                int brow = wn * 32 + nf * 16 + lm;
                int bby = brow * 128 + ((ks * 64 + lk * 16) ^ ((brow & 7) << 4));
                bf16x8 b1 = *(const bf16x8*)(B1s + bby);
                bf16x8 b3 = *(const bf16x8*)(B3s + bby);
#pragma unroll
                for (int mf = 0; mf < 4; ++mf) {
                    acc1[mf][nf] = __builtin_amdgcn_mfma_f32_16x16x32_bf16(af[mf], b1, acc1[mf][nf], 0, 0, 0);
                    acc3[mf][nf] = __builtin_amdgcn_mfma_f32_16x16x32_bf16(af[mf], b3, acc3[mf][nf], 0, 0, 0);
                }
            }
        }
    }

#pragma unroll
    for (int mf = 0; mf < 4; ++mf)
#pragma unroll
        for (int nf = 0; nf < 2; ++nf) {
            int coli = i0 + wn * 32 + nf * 16 + lm;
#pragma unroll
            for (int j = 0; j < 4; ++j) {
                int rloc = wm * 64 + mf * 16 + lk * 4 + j;
                if (p0 + rloc < c) {
                    float h1 = acc1[mf][nf][j];
                    float val = h1 / (1.f + __expf(-h1)) * acc3[mf][nf][j];
                    hbuf[(size_t)rowslotS[rloc] * I_ + coli] = f2bf(val);
                }
            }
        }
}

// ---------------- MoE down (reg-staged, WB=false fallback)
template<bool WB>
__global__ __launch_bounds__(256) void moe_dn_mfma(const unsigned short* __restrict__ hbuf,
                                                   const void* __restrict__ w2,
                                                   const int* __restrict__ cnt,
                                                   const int* __restrict__ eslot,
                                                   unsigned short* __restrict__ dbuf)
{
    int e = blockIdx.z >> 2;
    int slice = blockIdx.z & 3;
    int c = cnt[e];
    int p0 = blockIdx.y * 128;
    if (p0 >= c) return;
    int h0 = blockIdx.x * 128;
    int tid = threadIdx.x;
    const int kb0 = slice * (I_ / KSLC);

    __shared__ char As[16384], Bs[16384];
    __shared__ int rowslotS[128];
    if (tid < 128) rowslotS[tid] = eslot[e * S_ + min(p0 + tid, c - 1)];
    __syncthreads();

    int lane = tid & 63, w = tid >> 6, wm = w >> 1, wn = w & 1;
    int lm = lane & 15, lk = lane >> 4;
    size_t wbase = (size_t)e * H_ * I_;

    int4 rA[4], rB[4];
    auto loadAll = [&](int kb) {
#pragma unroll
        for (int it = 0; it < 4; ++it) {
            int g = tid + it * 256, row = g >> 3, kg = g & 7;
            rA[it] = *(const int4*)(hbuf + (size_t)rowslotS[row] * I_ + kb + kg * 8);
            rB[it] = loadW16<WB>(w2, wbase + (size_t)(h0 + row) * I_ + kb + kg * 8);
        }
    };
    auto writeAll = [&]() {
#pragma unroll
        for (int it = 0; it < 4; ++it) {
            int g = tid + it * 256, row = g >> 3, kg = g & 7;
            int byte = row * 128 + ((kg * 16) ^ ((row & 7) << 4));
            *(int4*)(As + byte) = rA[it];
            *(int4*)(Bs + byte) = rB[it];
        }
    };

    f32x4 z = {0.f, 0.f, 0.f, 0.f};
    f32x4 acc[4][4];
#pragma unroll
    for (int mf = 0; mf < 4; ++mf)
#pragma unroll
        for (int nf = 0; nf < 4; ++nf) acc[mf][nf] = z;

    loadAll(kb0);
    const int NKT = (I_ / KSLC) / 64;
    for (int kt = 0; kt < NKT; ++kt) {
        __syncthreads();
        writeAll();
        __syncthreads();
        if (kt + 1 < NKT) loadAll(kb0 + (kt + 1) * 64);
#pragma unroll
        for (int ks = 0; ks < 2; ++ks) {
            bf16x8 af[4];
#pragma unroll
            for (int mf = 0; mf < 4; ++mf) {
                int row = wm * 64 + mf * 16 + lm;
                af[mf] = *(const bf16x8*)(As + row * 128 + ((ks * 64 + lk * 16) ^ ((row & 7) << 4)));
            }
#pragma unroll
            for (int nf = 0; nf < 4; ++nf) {
                int brow = wn * 64 + nf * 16 + lm;
                bf16x8 bf = *(const bf16x8*)(Bs + brow * 128 + ((ks * 64 + lk * 16) ^ ((brow & 7) << 4)));
#pragma unroll
                for (int mf = 0; mf < 4; ++mf)
                    acc[mf][nf] = __builtin_amdgcn_mfma_f32_16x16x32_bf16(af[mf], bf, acc[mf][nf], 0, 0, 0);
            }
        }
    }

    unsigned short* dslice = dbuf + (size_t)slice * S_ * 2 * H_;
#pragma unroll
    for (int mf = 0; mf < 4; ++mf)
#pragma unroll
        for (int nf = 0; nf < 4; ++nf) {
            int colh = h0 + wn * 64 + nf * 16 + lm;
#pragma unroll
            for (int j = 0; j < 4; ++j) {
                int rloc = wm * 64 + mf * 16 + lk * 4 + j;
                if (p0 + rloc < c)
                    dslice[(size_t)rowslotS[rloc] * H_ + colh] = f2bf(acc[mf][nf][j]);
            }
        }
}

// ---------------- Final combine
__global__ __launch_bounds__(256) void combine_k(const float* __restrict__ hid2,
                                                 const unsigned short* __restrict__ dbuf,
                                                 const float* __restrict__ wslot,
                                                 float* __restrict__ out)
{
    int idx = blockIdx.x * 256 + threadIdx.x;
    if (idx >= S_ * H_) return;
    int n = idx >> 10;
    int hcol = idx & (H_ - 1);
    float s0 = 0.f, s1 = 0.f;
#pragma unroll
    for (int sl = 0; sl < KSLC; ++sl) {
        const unsigned short* base = dbuf + (size_t)sl * S_ * 2 * H_;
        s0 += bf2f(base[(size_t)(2 * n)     * H_ + hcol]);
        s1 += bf2f(base[(size_t)(2 * n + 1) * H_ + hcol]);
    }
    out[idx] = hid2[idx] + wslot[2 * n] * s0 + wslot[2 * n + 1] * s1;
}

extern "C" void kernel_launch(void* const* d_in, const int* in_sizes, int n_in,
                              void* d_out, int out_size, void* d_ws, size_t ws_size,
                              hipStream_t stream)
{
    const float* hidden = (const float*)d_in[0];
    const float* ln1    = (const float*)d_in[1];
    const float* ln2    = (const float*)d_in[2];
    const float* wq     = (const float*)d_in[3];
    const float* wk     = (const float*)d_in[4];
    const float* wv     = (const float*)d_in[5];
    const float* wo     = (const float*)d_in[6];
    const float* gw     = (const float*)d_in[7];
    const float* w1     = (const float*)d_in[8];
    const float* w2     = (const float*)d_in[9];
    const float* w3     = (const float*)d_in[10];
    float* out = (float*)d_out;

    char* p = (char*)d_ws;
    auto alignp = [&]() { p = (char*)(((uintptr_t)p + 255) & ~(uintptr_t)255); };
    auto alloc_f = [&](size_t n) { alignp(); float* r = (float*)p; p += n * 4; return r; };
    auto alloc_h = [&](size_t n) { alignp(); unsigned short* r = (unsigned short*)p; p += n * 2; return r; };
    auto alloc_i = [&](size_t n) { alignp(); int* r = (int*)p; p += n * 4; return r; };

    float* xb   = alloc_f((size_t)S_ * H_);
    unsigned short* xbb = alloc_h((size_t)S_ * H_);
    float* q    = alloc_f((size_t)S_ * NH_ * HD_);
    float* kb   = alloc_f((size_t)S_ * KVH_ * HD_);
    float* vb   = alloc_f((size_t)S_ * KVH_ * HD_);
    unsigned short* qkvb = alloc_h((size_t)S_ * 2048);
    float* hid2 = alloc_f((size_t)S_ * H_);
    float* x2   = alloc_f((size_t)S_ * H_);
    unsigned short* x2b  = alloc_h((size_t)S_ * H_);
    unsigned short* ctxb = alloc_h((size_t)S_ * H_);
    unsigned short* hbuf = alloc_h((size_t)S_ * 2 * I_);
    unsigned short* dbuf = alloc_h((size_t)KSLC * S_ * 2 * H_);
    float* wslot= alloc_f((size_t)S_ * 2);
    unsigned short* qbf = alloc_h((size_t)S_ * NH_ * HD_);
    unsigned short* kbf = alloc_h((size_t)S_ * KVH_ * HD_);
    unsigned short* vtb = alloc_h((size_t)KVH_ * HD_ * S_);
    int* cnt   = alloc_i(E_);
    int* elist = alloc_i((size_t)E_ * S_);
    int* eslot = alloc_i((size_t)E_ * S_);
    float* ctx = xb;  // fallback alias

    size_t used = (size_t)(p - (char*)d_ws);
    const size_t nW = (size_t)E_ * I_ * H_;
    size_t wbf_bytes = (3 * nW + (size_t)2048 * H_ + (size_t)H_ * NH_ * HD_) * 2 + 8192;
    bool WB = ws_size > used && (ws_size - used) >= wbf_bytes;

    unsigned short *w1b = nullptr, *w3b = nullptr, *w2b = nullptr;
    unsigned short *wqkvb = nullptr, *wob = nullptr;
    if (WB) {
        w1b = alloc_h(nW); w3b = alloc_h(nW); w2b = alloc_h(nW);
        wqkvb = alloc_h((size_t)2048 * H_);
        wob = alloc_h((size_t)H_ * NH_ * HD_);
    }

    hipMemsetAsync(cnt, 0, E_ * sizeof(int), stream);

    if (WB) {
        conv3<<<dim3(2048, 3), 256, 0, stream>>>(w1, w3, w2, w1b, w3b, w2b, (long)(nW / 8));
        conv_qkvo<<<1536, 256, 0, stream>>>(wq, wk, wv, wo, wqkvb, wob);

        rmsnorm_k<<<S_, 256, 0, stream>>>(hidden, ln1, nullptr, xbb);
        dense_g<false><<<dim3(32, 16), 256, 0, stream>>>(xbb, wqkvb, nullptr, qkvb, H_, 2048);
        {
            int tot = S_ * (NH_ + KVH_) * 32;
            rope_conv_b<<<SDIV(tot, 256), 256, 0, stream>>>(qkvb, qbf, kbf);
        }
        v_trans_b<<<dim3(S_ / 64, KVH_), 256, 0, stream>>>(qkvb, vtb);
        attn_mfma<<<dim3(16, NH_, 2), 256, 0, stream>>>(qbf, kbf, vtb, nullptr, ctxb);
        dense_g<true><<<dim3(16, 16), 256, 0, stream>>>(ctxb, wob, hidden, hid2, H_, H_);

        rms2router<<<S_, 256, 0, stream>>>(hid2, ln2, gw, x2b, cnt, elist, eslot, wslot);

        moe_up_g<<<dim3(I_ / 64, S_ / 128, E_), 256, 0, stream>>>(x2b, w1b, w3b, cnt, elist, eslot, hbuf);
        moe_dn_g<<<dim3(H_ / 128, S_ / 128, E_ * KSLC), 256, 0, stream>>>(hbuf, w2b, cnt, eslot, dbuf);
    } else {
        rmsnorm_k<<<S_, 256, 0, stream>>>(hidden, ln1, xb, nullptr);
        dense_mfma<false><<<dim3(8, 16), 256, 0, stream>>>(xb, wq, nullptr, q,  S_, NH_ * HD_, H_);
        dense_mfma<false><<<dim3(4, 16), 256, 0, stream>>>(xb, wk, nullptr, kb, S_, KVH_ * HD_, H_);
        dense_mfma<false><<<dim3(4, 16), 256, 0, stream>>>(xb, wv, nullptr, vb, S_, KVH_ * HD_, H_);
        {
            int tot = S_ * (NH_ + KVH_) * 32;
            rope_conv<<<SDIV(tot, 256), 256, 0, stream>>>(q, kb, qbf, kbf);
        }
        v_trans<<<dim3(S_ / 64, KVH_), 256, 0, stream>>>(vb, vtb);
        attn_mfma<<<dim3(16, NH_, 2), 256, 0, stream>>>(qbf, kbf, vtb, ctx, ctxb);
        dense_mfma<false><<<dim3(8, 16), 256, 0, stream>>>(ctx, wo, hidden, hid2, S_, H_, NH_ * HD_);

        rmsnorm_k<<<S_, 256, 0, stream>>>(hid2, ln2, x2, nullptr);
        router_k<<<S_, 64, 0, stream>>>(x2, gw, cnt, elist, eslot, wslot);

        moe_up_mfma<false><<<dim3(I_ / 64, S_ / 128, E_), 256, 0, stream>>>(x2, w1, w3, cnt, elist, eslot, hbuf);
        moe_dn_mfma<false><<<dim3(H_ / 128, S_ / 128, E_ * KSLC), 256, 0, stream>>>(hbuf, w2, cnt, eslot, dbuf);
    }
    combine_k<<<SDIV(S_ * H_, 256), 256, 0, stream>>>(hid2, dbuf, wslot, out);
}